// Round 1
// baseline (1121.485 us; speedup 1.0000x reference)
//
#include <hip/hip_runtime.h>
#include <math.h>

namespace {
constexpr int Bc   = 1024;
constexpr int Lc   = 200;
constexpr int Dc   = 64;
constexpr int Ec   = 32;
constexpr int Pc   = 96;    // D+E
constexpr int Hc   = 256;
constexpr int Tc   = 8;
constexpr int NLc  = 3;
constexpr int KINc = 272;   // H+2T
constexpr int DHc  = 64;
constexpr int Cc   = 32;
constexpr int QKW  = 1088;  // NH*KIN
constexpr float LN_EPS_V = 1e-5f;
constexpr float NEG_BIG  = -1e9f;
}

// ---------------- Wqk[i][e][hh*272+j] = sum_d Wq[i,e,hh*64+d] * Wk[i,j,hh*64+d]
__global__ __launch_bounds__(256) void k_wqk(const float* __restrict__ Wq,
                                             const float* __restrict__ Wk,
                                             float* __restrict__ wqk) {
    int blk = blockIdx.x;           // NLc*Hc blocks
    int i = blk >> 8;
    int e = blk & 255;
    int t = threadIdx.x;
    __shared__ float qrow[Hc];
    qrow[t] = Wq[i * Hc * Hc + e * Hc + t];
    __syncthreads();
    const float* wkL = Wk + (size_t)i * KINc * Hc;
    for (int c = t; c < QKW; c += 256) {
        int hh = c / KINc;
        int j  = c - hh * KINc;
        const float* wkr = wkL + j * Hc + hh * DHc;
        const float* qr  = qrow + hh * DHc;
        float acc = 0.f;
        #pragma unroll
        for (int d = 0; d < DHc; ++d) acc += qr[d] * wkr[d];
        wqk[(size_t)i * Hc * QKW + e * QKW + c] = acc;
    }
}

// ---------------- h0 = [x_u, emb[act_u]] @ W_in_self + b
__global__ __launch_bounds__(256) void k_h0(const float* __restrict__ x_u,
                                            const int* __restrict__ act_u,
                                            const float* __restrict__ emb,
                                            const float* __restrict__ W,
                                            const float* __restrict__ bias,
                                            float* __restrict__ h) {
    constexpr int R = 16;
    int b0 = blockIdx.x * R;
    int t = threadIdx.x;
    __shared__ float xu[R * Pc];
    for (int idx = t; idx < R * Pc; idx += 256) {
        int r = idx / Pc, j = idx - r * Pc;
        int b = b0 + r;
        float v;
        if (j < Dc) v = x_u[b * Dc + j];
        else        v = emb[act_u[b] * Ec + (j - Dc)];
        xu[idx] = v;
    }
    __syncthreads();
    float acc[R];
    float bb = bias[t];
    #pragma unroll
    for (int r = 0; r < R; ++r) acc[r] = bb;
    for (int j = 0; j < Pc; ++j) {
        float w = W[j * Hc + t];
        #pragma unroll
        for (int r = 0; r < R; ++r) acc[r] += xu[r * Pc + j] * w;
    }
    #pragma unroll
    for (int r = 0; r < R; ++r) h[(b0 + r) * Hc + t] = acc[r];
}

// ---------------- ctx = [x_ctx, emb[act_ctx]] @ W_in_ctx + b   (204800 x 96 @ 96 x 256)
__global__ __launch_bounds__(256) void k_ctx(const float* __restrict__ x_ctx,
                                             const int* __restrict__ act_ctx,
                                             const float* __restrict__ emb,
                                             const float* __restrict__ W,
                                             const float* __restrict__ bias,
                                             float* __restrict__ ctx) {
    constexpr int R = 32;
    int row0 = blockIdx.x * R;      // row = b*L + l
    int t = threadIdx.x;
    __shared__ float xc[R * Pc];
    for (int idx = t; idx < R * Pc; idx += 256) {
        int r = idx / Pc, j = idx - r * Pc;
        int row = row0 + r;
        float v;
        if (j < Dc) v = x_ctx[(size_t)row * Dc + j];
        else        v = emb[act_ctx[row] * Ec + (j - Dc)];
        xc[idx] = v;
    }
    __syncthreads();
    float acc[R];
    float bb = bias[t];
    #pragma unroll
    for (int r = 0; r < R; ++r) acc[r] = bb;
    for (int j = 0; j < Pc; ++j) {
        float w = W[j * Hc + t];
        #pragma unroll
        for (int r = 0; r < R; ++r) acc[r] += xc[r * Pc + j] * w;
    }
    #pragma unroll
    for (int r = 0; r < R; ++r) ctx[(size_t)(row0 + r) * Hc + t] = acc[r];
}

// ---------------- qk = h @ Wqk[i]   (1024x256 @ 256x1088)
__global__ __launch_bounds__(256) void k_qk(const float* __restrict__ h,
                                            const float* __restrict__ wqk_l,
                                            float* __restrict__ qk) {
    constexpr int R = 32;
    int rb = blockIdx.x & 31;
    int cc = blockIdx.x >> 5;       // 0..4
    int b0 = rb * R;
    int t = threadIdx.x;
    int c = cc * 256 + t;
    __shared__ float hl[R * Hc];
    for (int idx = t; idx < R * Hc; idx += 256) hl[idx] = h[b0 * Hc + idx];
    __syncthreads();
    if (c >= QKW) return;
    float acc[R];
    #pragma unroll
    for (int r = 0; r < R; ++r) acc[r] = 0.f;
    for (int e = 0; e < Hc; ++e) {
        float w = wqk_l[(size_t)e * QKW + c];
        #pragma unroll
        for (int r = 0; r < R; ++r) acc[r] += hl[r * Hc + e] * w;
    }
    #pragma unroll
    for (int r = 0; r < R; ++r) qk[(size_t)(b0 + r) * QKW + c] = acc[r];
}

// ---------------- flash-decode attention: one block per b; wave = head
// out: cagg[b, hh*272+j] = sum_l softmax(logits)[hh,l] * kv[b,l,j]
__global__ __launch_bounds__(256) void k_att(const float* __restrict__ ctx,
                                             const float* __restrict__ qk,
                                             const float* __restrict__ t_ctx,
                                             const int* __restrict__ act_ctx,
                                             const float* __restrict__ freq,
                                             const float* __restrict__ phase,
                                             float* __restrict__ cagg, int layer) {
    constexpr int TL = 32;
    constexpr int STRIDE = KINc + 1;    // 273, odd -> conflict-free row access
    int b = blockIdx.x;
    int t = threadIdx.x;
    int wave = t >> 6;                  // head
    int lane = t & 63;
    int half = lane >> 5;
    int ll = lane & 31;

    __shared__ float kv[TL * STRIDE];
    __shared__ float qkl[QKW];
    for (int idx = t; idx < QKW; idx += 256) qkl[idx] = qk[(size_t)b * QKW + idx];

    int tf = t & 7;
    float fr = freq[layer * Tc + tf];
    float ph = phase[layer * Tc + tf];

    float m = -INFINITY, s = 0.f;
    float agg[5] = {0.f, 0.f, 0.f, 0.f, 0.f};
    const float inv_scale = 0.125f;     // 1/sqrt(64)

    for (int l0 = 0; l0 < Lc; l0 += TL) {
        __syncthreads();
        // stage ctx tile (coalesced global, stride-1 LDS stores -> conflict-free)
        for (int r = 0; r < TL; ++r) {
            int l = l0 + r;
            kv[r * STRIDE + t] = (l < Lc) ? ctx[(size_t)(b * Lc + l) * Hc + t] : 0.f;
        }
        // te columns 256..271: thread -> (row = t>>3, f = t&7)
        {
            int r = t >> 3;
            int l = l0 + r;
            float tc = (l < Lc) ? t_ctx[b * Lc + l] : 0.f;
            float lt = log1pf(fmaxf(tc, 0.f));
            float z = lt * fr + ph;
            kv[r * STRIDE + Hc + tf]      = __sinf(z);
            kv[r * STRIDE + Hc + Tc + tf] = __cosf(z);
        }
        __syncthreads();

        // logits for (head=wave, l=l0+ll); halves split the 272-dot
        int l = l0 + ll;
        float acc = 0.f;
        {
            const float* kvr = kv + ll * STRIDE + half * 136;
            const float* qp  = qkl + wave * KINc + half * 136;
            #pragma unroll 8
            for (int cci = 0; cci < 136; ++cci) acc += kvr[cci] * qp[cci];
        }
        acc += __shfl_xor(acc, 32);     // both halves now hold full dot

        bool valid = (l < Lc);
        float logit;
        if (valid) {
            bool msk = act_ctx[b * Lc + l] > 0;
            logit = msk ? acc * inv_scale : NEG_BIG;
        } else {
            logit = -INFINITY;
        }
        // tile max / sum over the 32 l's (halves identical)
        float tmax = logit;
        #pragma unroll
        for (int off = 16; off >= 1; off >>= 1) tmax = fmaxf(tmax, __shfl_xor(tmax, off));
        float mnew = fmaxf(m, tmax);
        float fac = __expf(m - mnew);
        float p = valid ? __expf(logit - mnew) : 0.f;
        float psum = p;
        #pragma unroll
        for (int off = 16; off >= 1; off >>= 1) psum += __shfl_xor(psum, off);
        s = s * fac + psum;
        m = mnew;
        #pragma unroll
        for (int k = 0; k < 5; ++k) agg[k] *= fac;
        // ctxagg accumulate: j = lane + 64k over 272 kv columns
        for (int li = 0; li < TL; ++li) {
            float pl = __shfl(p, li);
            const float* kvr = kv + li * STRIDE;
            #pragma unroll
            for (int k = 0; k < 5; ++k) {
                int j = lane + 64 * k;
                if (j < KINc) agg[k] += pl * kvr[j];
            }
        }
    }
    float sinv = 1.f / s;
    #pragma unroll
    for (int k = 0; k < 5; ++k) {
        int j = lane + 64 * k;
        if (j < KINc) cagg[(size_t)b * QKW + wave * KINc + j] = agg[k] * sinv;
    }
}

// ---------------- post-attention: aggproj + h@Wres + LN1 + FF + LN2 -> h (in place)
__global__ __launch_bounds__(256) void k_post(const float* __restrict__ cagg,
                                              float* __restrict__ h,
                                              const float* __restrict__ Wv,
                                              const float* __restrict__ Wres,
                                              const float* __restrict__ bres,
                                              const float* __restrict__ Wff1,
                                              const float* __restrict__ bff1,
                                              const float* __restrict__ Wff2,
                                              const float* __restrict__ bff2,
                                              const float* __restrict__ g1,
                                              const float* __restrict__ beta1,
                                              const float* __restrict__ g2,
                                              const float* __restrict__ beta2,
                                              int layer) {
    constexpr int R = 4;
    int b0 = blockIdx.x * R;
    int t = threadIdx.x;
    int wave = t >> 6, lane = t & 63;
    __shared__ float hl[R * Hc];
    __shared__ float cg[R * QKW];
    __shared__ float z1[R * Hc];
    __shared__ float ffa[R * Hc];
    __shared__ float red[R][2];
    for (int idx = t; idx < R * Hc; idx += 256) hl[idx] = h[b0 * Hc + idx];
    for (int idx = t; idx < R * QKW; idx += 256) cg[idx] = cagg[(size_t)b0 * QKW + idx];
    __syncthreads();

    const float* WvL   = Wv   + (size_t)layer * KINc * Hc;
    const float* WresL = Wres + (size_t)layer * Hc * Hc;
    int hh = t >> 6;
    float acc[R];
    float bb = bres[layer * Hc + t];
    #pragma unroll
    for (int r = 0; r < R; ++r) acc[r] = bb;
    for (int j = 0; j < KINc; ++j) {
        float w = WvL[j * Hc + t];
        #pragma unroll
        for (int r = 0; r < R; ++r) acc[r] += cg[r * QKW + hh * KINc + j] * w;
    }
    for (int d = 0; d < Hc; ++d) {
        float w = WresL[d * Hc + t];
        #pragma unroll
        for (int r = 0; r < R; ++r) acc[r] += hl[r * Hc + d] * w;
    }
    // ---- LN1
    #pragma unroll
    for (int r = 0; r < R; ++r) z1[r * Hc + t] = acc[r];
    __syncthreads();
    {
        int r = wave;   // 4 waves, 4 rows
        float v0 = z1[r * Hc + lane], v1 = z1[r * Hc + lane + 64];
        float v2 = z1[r * Hc + lane + 128], v3 = z1[r * Hc + lane + 192];
        float sm = v0 + v1 + v2 + v3;
        float sq = v0 * v0 + v1 * v1 + v2 * v2 + v3 * v3;
        #pragma unroll
        for (int off = 32; off >= 1; off >>= 1) { sm += __shfl_xor(sm, off); sq += __shfl_xor(sq, off); }
        if (lane == 0) {
            float mu = sm * (1.f / Hc);
            float var = sq * (1.f / Hc) - mu * mu;
            red[r][0] = mu;
            red[r][1] = rsqrtf(var + LN_EPS_V);
        }
    }
    __syncthreads();
    float z1v[R];
    float g1t = g1[layer * Hc + t], b1t = beta1[layer * Hc + t];
    #pragma unroll
    for (int r = 0; r < R; ++r) {
        z1v[r] = (acc[r] - red[r][0]) * red[r][1] * g1t + b1t;
        z1[r * Hc + t] = z1v[r];
    }
    __syncthreads();
    // ---- FF1
    const float* W1 = Wff1 + (size_t)layer * Hc * Hc;
    float f1[R];
    float bf1 = bff1[layer * Hc + t];
    #pragma unroll
    for (int r = 0; r < R; ++r) f1[r] = bf1;
    for (int d = 0; d < Hc; ++d) {
        float w = W1[d * Hc + t];
        #pragma unroll
        for (int r = 0; r < R; ++r) f1[r] += z1[r * Hc + d] * w;
    }
    #pragma unroll
    for (int r = 0; r < R; ++r) ffa[r * Hc + t] = fmaxf(f1[r], 0.f);
    __syncthreads();
    // ---- FF2 + residual
    const float* W2 = Wff2 + (size_t)layer * Hc * Hc;
    float y[R];
    float bf2 = bff2[layer * Hc + t];
    #pragma unroll
    for (int r = 0; r < R; ++r) y[r] = z1v[r] + bf2;
    for (int d = 0; d < Hc; ++d) {
        float w = W2[d * Hc + t];
        #pragma unroll
        for (int r = 0; r < R; ++r) y[r] += ffa[r * Hc + d] * w;
    }
    // ---- LN2 -> h
    __syncthreads();
    #pragma unroll
    for (int r = 0; r < R; ++r) z1[r * Hc + t] = y[r];
    __syncthreads();
    {
        int r = wave;
        float v0 = z1[r * Hc + lane], v1 = z1[r * Hc + lane + 64];
        float v2 = z1[r * Hc + lane + 128], v3 = z1[r * Hc + lane + 192];
        float sm = v0 + v1 + v2 + v3;
        float sq = v0 * v0 + v1 * v1 + v2 * v2 + v3 * v3;
        #pragma unroll
        for (int off = 32; off >= 1; off >>= 1) { sm += __shfl_xor(sm, off); sq += __shfl_xor(sq, off); }
        if (lane == 0) {
            float mu = sm * (1.f / Hc);
            float var = sq * (1.f / Hc) - mu * mu;
            red[r][0] = mu;
            red[r][1] = rsqrtf(var + LN_EPS_V);
        }
    }
    __syncthreads();
    float g2t = g2[layer * Hc + t], b2t = beta2[layer * Hc + t];
    #pragma unroll
    for (int r = 0; r < R; ++r)
        h[(b0 + r) * Hc + t] = (y[r] - red[r][0]) * red[r][1] * g2t + b2t;
}

// ---------------- head: z = relu(h@W_ro+b); logits/dt/rem
__global__ __launch_bounds__(256) void k_head(const float* __restrict__ h,
                                              const float* __restrict__ W_ro,
                                              const float* __restrict__ b_ro,
                                              const float* __restrict__ W_cls,
                                              const float* __restrict__ b_cls,
                                              const float* __restrict__ W_dt,
                                              const float* __restrict__ b_dt,
                                              const float* __restrict__ W_rem,
                                              const float* __restrict__ b_rem,
                                              float* __restrict__ out) {
    constexpr int R = 8;
    int b0 = blockIdx.x * R;
    int t = threadIdx.x;
    int wave = t >> 6, lane = t & 63;
    __shared__ float hl[R * Hc], zl[R * Hc];
    __shared__ float wcls[Hc * Cc];
    __shared__ float wdt[Hc], wrem[Hc];
    for (int idx = t; idx < R * Hc; idx += 256) hl[idx] = h[b0 * Hc + idx];
    for (int idx = t; idx < Hc * Cc; idx += 256) wcls[idx] = W_cls[idx];
    wdt[t] = W_dt[t];
    wrem[t] = W_rem[t];
    __syncthreads();
    float acc[R];
    float br = b_ro[t];
    #pragma unroll
    for (int r = 0; r < R; ++r) acc[r] = br;
    for (int d = 0; d < Hc; ++d) {
        float w = W_ro[d * Hc + t];    // MLP == H == 256
        #pragma unroll
        for (int r = 0; r < R; ++r) acc[r] += hl[r * Hc + d] * w;
    }
    #pragma unroll
    for (int r = 0; r < R; ++r) zl[r * Hc + t] = fmaxf(acc[r], 0.f);
    __syncthreads();
    // logits: thread -> (row = t>>5, col = t&31)
    {
        int rr = t >> 5;
        int c = t & 31;
        float a = b_cls[c];
        for (int d = 0; d < Hc; ++d) a += zl[rr * Hc + d] * wcls[d * Cc + c];
        out[(size_t)(b0 + rr) * Cc + c] = a;
    }
    // dt / rem: wave w handles rows 2w, 2w+1
    for (int rr = wave * 2; rr < wave * 2 + 2; ++rr) {
        float sd = 0.f, sr = 0.f;
        #pragma unroll
        for (int k2 = 0; k2 < 4; ++k2) {
            float zv = zl[rr * Hc + lane + 64 * k2];
            sd += zv * wdt[lane + 64 * k2];
            sr += zv * wrem[lane + 64 * k2];
        }
        #pragma unroll
        for (int off = 32; off >= 1; off >>= 1) { sd += __shfl_xor(sd, off); sr += __shfl_xor(sr, off); }
        if (lane == 0) {
            out[(size_t)Bc * Cc + b0 + rr]      = 1.f / (1.f + __expf(-(sd + b_dt[0])));
            out[(size_t)Bc * Cc + Bc + b0 + rr] = 1.f / (1.f + __expf(-(sr + b_rem[0])));
        }
    }
}

extern "C" void kernel_launch(void* const* d_in, const int* in_sizes, int n_in,
                              void* d_out, int out_size, void* d_ws, size_t ws_size,
                              hipStream_t stream) {
    const float* x_u      = (const float*)d_in[0];
    const float* x_ctx    = (const float*)d_in[1];
    const float* t_ctx    = (const float*)d_in[2];
    const int*   act_u    = (const int*)d_in[3];
    const int*   act_ctx  = (const int*)d_in[4];
    const float* emb      = (const float*)d_in[5];
    const float* W_in_self = (const float*)d_in[6];
    const float* b_in_self = (const float*)d_in[7];
    const float* W_in_ctx  = (const float*)d_in[8];
    const float* b_in_ctx  = (const float*)d_in[9];
    const float* freq  = (const float*)d_in[10];
    const float* phase = (const float*)d_in[11];
    const float* Wq    = (const float*)d_in[12];
    const float* Wk    = (const float*)d_in[13];
    const float* Wv    = (const float*)d_in[14];
    const float* Wres  = (const float*)d_in[15];
    const float* bres  = (const float*)d_in[16];
    const float* Wff1  = (const float*)d_in[17];
    const float* bff1  = (const float*)d_in[18];
    const float* Wff2  = (const float*)d_in[19];
    const float* bff2  = (const float*)d_in[20];
    const float* g1    = (const float*)d_in[21];
    const float* beta1 = (const float*)d_in[22];
    const float* g2    = (const float*)d_in[23];
    const float* beta2 = (const float*)d_in[24];
    const float* W_ro  = (const float*)d_in[25];
    const float* b_ro  = (const float*)d_in[26];
    const float* W_cls = (const float*)d_in[27];
    const float* b_cls = (const float*)d_in[28];
    const float* W_dt  = (const float*)d_in[29];
    const float* b_dt  = (const float*)d_in[30];
    const float* W_rem = (const float*)d_in[31];
    const float* b_rem = (const float*)d_in[32];

    float* ws   = (float*)d_ws;
    float* ctx  = ws;                                   // B*L*H
    float* hbuf = ctx  + (size_t)Bc * Lc * Hc;          // B*H
    float* wqk  = hbuf + (size_t)Bc * Hc;               // NL*H*QKW
    float* qk   = wqk  + (size_t)NLc * Hc * QKW;        // B*QKW
    float* cagg = qk   + (size_t)Bc * QKW;              // B*QKW
    size_t need_bytes = (size_t)(cagg + (size_t)Bc * QKW - ws) * sizeof(float);
    if (ws_size < need_bytes) return;   // workspace too small; fail loudly via absmax

    float* out = (float*)d_out;

    k_wqk<<<NLc * Hc, 256, 0, stream>>>(Wq, Wk, wqk);
    k_h0<<<Bc / 16, 256, 0, stream>>>(x_u, act_u, emb, W_in_self, b_in_self, hbuf);
    k_ctx<<<(Bc * Lc) / 32, 256, 0, stream>>>(x_ctx, act_ctx, emb, W_in_ctx, b_in_ctx, ctx);

    for (int i = 0; i < NLc; ++i) {
        k_qk<<<160, 256, 0, stream>>>(hbuf, wqk + (size_t)i * Hc * QKW, qk);
        k_att<<<Bc, 256, 0, stream>>>(ctx, qk, t_ctx, act_ctx, freq, phase, cagg, i);
        k_post<<<Bc / 4, 256, 0, stream>>>(cagg, hbuf, Wv, Wres, bres,
                                           Wff1, bff1, Wff2, bff2,
                                           g1, beta1, g2, beta2, i);
    }
    k_head<<<Bc / 8, 256, 0, stream>>>(hbuf, W_ro, b_ro, W_cls, b_cls,
                                       W_dt, b_dt, W_rem, b_rem, out);
}

// Round 2
// 605.114 us; speedup vs baseline: 1.8533x; 1.8533x over previous
//
#include <hip/hip_runtime.h>
#include <math.h>

namespace {
constexpr int Bc   = 1024;
constexpr int Lc   = 200;
constexpr int Dc   = 64;
constexpr int Ec   = 32;
constexpr int Pc   = 96;    // D+E
constexpr int Hc   = 256;
constexpr int Tc   = 8;
constexpr int NLc  = 3;
constexpr int KINc = 272;   // H+2T
constexpr int DHc  = 64;
constexpr int Cc   = 32;
constexpr int QKW  = 1088;  // NH*KIN
constexpr float LN_EPS_V = 1e-5f;
constexpr float NEG_BIG  = -1e9f;

typedef __attribute__((ext_vector_type(8))) short bf16x8;
typedef __attribute__((ext_vector_type(4))) float f32x4;

__device__ __forceinline__ unsigned short f2bf(float f) {
    union { float f; unsigned int u; } v; v.f = f;
    unsigned int u = v.u;
    unsigned int r = (u + 0x7fffu + ((u >> 16) & 1u)) >> 16;
    return (unsigned short)r;
}
__device__ __forceinline__ float bf2f(unsigned short us) {
    union { unsigned int u; float f; } v; v.u = ((unsigned int)us) << 16;
    return v.f;
}
}

// ---------------- build swizzled bf16 B-fragments of W_in_ctx (96x256)
// frag f = (kk,ct,lane): 8 bf16 = W[kk*32 + (lane>>4)*8 + j][ct*16 + (lane&15)]
__global__ __launch_bounds__(256) void k_prep_wswz(const float* __restrict__ W,
                                                   unsigned short* __restrict__ wswz) {
    int f = blockIdx.x * 256 + threadIdx.x;     // 12*256 = 3072 frags
    if (f >= 3 * 16 * 64) return;
    int kk = f >> 10;
    int r  = f & 1023;
    int ct = r >> 6;
    int lane = r & 63;
    int kb = kk * 32 + (lane >> 4) * 8;
    int col = ct * 16 + (lane & 15);
    unsigned short tmp[8];
    #pragma unroll
    for (int j = 0; j < 8; ++j) tmp[j] = f2bf(W[(kb + j) * Hc + col]);
    uint4 v = *(const uint4*)tmp;
    *(uint4*)&wswz[(size_t)f * 8] = v;
}

// ---------------- Wqk[i][e][hh*272+j] = sum_d Wq[i,e,hh*64+d] * Wk[i,j,hh*64+d]
__global__ __launch_bounds__(256) void k_wqk(const float* __restrict__ Wq,
                                             const float* __restrict__ Wk,
                                             float* __restrict__ wqk) {
    int blk = blockIdx.x;           // NLc*Hc blocks
    int i = blk >> 8;
    int e = blk & 255;
    int t = threadIdx.x;
    __shared__ float qrow[Hc];
    qrow[t] = Wq[i * Hc * Hc + e * Hc + t];
    __syncthreads();
    const float* wkL = Wk + (size_t)i * KINc * Hc;
    for (int c = t; c < QKW; c += 256) {
        int hh = c / KINc;
        int j  = c - hh * KINc;
        const float* wkr = wkL + j * Hc + hh * DHc;
        const float* qr  = qrow + hh * DHc;
        float acc = 0.f;
        #pragma unroll
        for (int d = 0; d < DHc; ++d) acc += qr[d] * wkr[d];
        wqk[(size_t)i * Hc * QKW + e * QKW + c] = acc;
    }
}

// ---------------- h0 = [x_u, emb[act_u]] @ W_in_self + b
__global__ __launch_bounds__(256) void k_h0(const float* __restrict__ x_u,
                                            const int* __restrict__ act_u,
                                            const float* __restrict__ emb,
                                            const float* __restrict__ W,
                                            const float* __restrict__ bias,
                                            float* __restrict__ h) {
    constexpr int R = 16;
    int b0 = blockIdx.x * R;
    int t = threadIdx.x;
    __shared__ float xu[R * Pc];
    for (int idx = t; idx < R * Pc; idx += 256) {
        int r = idx / Pc, j = idx - r * Pc;
        int b = b0 + r;
        float v;
        if (j < Dc) v = x_u[b * Dc + j];
        else        v = emb[act_u[b] * Ec + (j - Dc)];
        xu[idx] = v;
    }
    __syncthreads();
    float acc[R];
    float bb = bias[t];
    #pragma unroll
    for (int r = 0; r < R; ++r) acc[r] = bb;
    for (int j = 0; j < Pc; ++j) {
        float w = W[j * Hc + t];
        #pragma unroll
        for (int r = 0; r < R; ++r) acc[r] += xu[r * Pc + j] * w;
    }
    #pragma unroll
    for (int r = 0; r < R; ++r) h[(b0 + r) * Hc + t] = acc[r];
}

// ---------------- ctx (bf16) = [x_ctx, emb[act_ctx]] @ W_in_ctx + b  via MFMA
// 64-row tile per block; 4 waves, each wave 16 rows x 256 cols.
__global__ __launch_bounds__(256) void k_ctx_mfma(const float* __restrict__ x_ctx,
                                                  const int* __restrict__ act_ctx,
                                                  const float* __restrict__ emb,
                                                  const unsigned short* __restrict__ wswz,
                                                  const float* __restrict__ bias,
                                                  unsigned short* __restrict__ ctxb) {
    __shared__ unsigned short sm[64 * 264];   // aliases: Xs [64][104] then out [64][264]
    __shared__ float biass[Hc];
    int t = threadIdx.x;
    int r0 = blockIdx.x * 64;
    biass[t] = bias[t];
    // stage Xs (bf16) rows r0..r0+63, 96 cols, LDS stride 104
    for (int idx = t; idx < 64 * 96; idx += 256) {
        int r = idx / 96, c = idx - r * 96;
        int row = r0 + r;
        float v = (c < Dc) ? x_ctx[(size_t)row * Dc + c]
                           : emb[act_ctx[row] * Ec + (c - Dc)];
        sm[r * 104 + c] = f2bf(v);
    }
    __syncthreads();
    int wv = t >> 6, lane = t & 63;
    int arow = wv * 16 + (lane & 15);
    int kbase = (lane >> 4) * 8;
    bf16x8 afr[3];
    #pragma unroll
    for (int kk = 0; kk < 3; ++kk)
        afr[kk] = *(const bf16x8*)&sm[arow * 104 + kk * 32 + kbase];
    __syncthreads();    // Xs consumed by all waves; sm now reusable as output stage

    int lrow = wv * 16 + (lane >> 4) * 4;
    int lc16 = lane & 15;
    #pragma unroll
    for (int ct = 0; ct < 16; ++ct) {
        f32x4 a = {0.f, 0.f, 0.f, 0.f};
        #pragma unroll
        for (int kk = 0; kk < 3; ++kk) {
            bf16x8 b = *((const bf16x8*)wswz + ((kk * 16 + ct) * 64 + lane));
            a = __builtin_amdgcn_mfma_f32_16x16x32_bf16(afr[kk], b, a, 0, 0, 0);
        }
        int col = ct * 16 + lc16;
        float bb = biass[col];
        #pragma unroll
        for (int q = 0; q < 4; ++q)
            sm[(lrow + q) * 264 + col] = f2bf(a[q] + bb);
    }
    __syncthreads();
    // coalesced copy-out: 64 rows x 256 cols bf16 = 2048 uint4
    for (int idx = t; idx < 64 * 32; idx += 256) {
        int r = idx >> 5, c4 = idx & 31;
        uint4 v = *(const uint4*)&sm[r * 264 + c4 * 8];
        *(uint4*)&ctxb[((size_t)(r0 + r)) * Hc + c4 * 8] = v;
    }
}

// ---------------- qk = h @ Wqk[i]   (1024x256 @ 256x1088)
__global__ __launch_bounds__(256) void k_qk(const float* __restrict__ h,
                                            const float* __restrict__ wqk_l,
                                            float* __restrict__ qk) {
    constexpr int R = 8;
    int rb = blockIdx.x & 127;
    int cc = blockIdx.x >> 7;       // 0..4
    int b0 = rb * R;
    int t = threadIdx.x;
    int c = cc * 256 + t;
    __shared__ float hl[R * Hc];
    for (int idx = t; idx < R * Hc; idx += 256) hl[idx] = h[b0 * Hc + idx];
    __syncthreads();
    if (c >= QKW) return;
    float acc[R];
    #pragma unroll
    for (int r = 0; r < R; ++r) acc[r] = 0.f;
    for (int e = 0; e < Hc; ++e) {
        float w = wqk_l[(size_t)e * QKW + c];
        #pragma unroll
        for (int r = 0; r < R; ++r) acc[r] += hl[r * Hc + e] * w;
    }
    #pragma unroll
    for (int r = 0; r < R; ++r) qk[(size_t)(b0 + r) * QKW + c] = acc[r];
}

// ---------------- flash-decode attention: one block per b; wave = head
__global__ __launch_bounds__(256) void k_att(const unsigned short* __restrict__ ctxb,
                                             const float* __restrict__ qk,
                                             const float* __restrict__ t_ctx,
                                             const int* __restrict__ act_ctx,
                                             const float* __restrict__ freq,
                                             const float* __restrict__ phase,
                                             float* __restrict__ cagg, int layer) {
    constexpr int TL = 32;
    constexpr int STRIDE = KINc + 1;    // 273
    int b = blockIdx.x;
    int t = threadIdx.x;
    int wave = t >> 6;                  // head
    int lane = t & 63;
    int half = lane >> 5;
    int ll = lane & 31;

    __shared__ float kv[TL * STRIDE];
    __shared__ float qkl[QKW];
    for (int idx = t; idx < QKW; idx += 256) qkl[idx] = qk[(size_t)b * QKW + idx];

    int tf = t & 7;
    float fr = freq[layer * Tc + tf];
    float ph = phase[layer * Tc + tf];

    float m = -INFINITY, s = 0.f;
    float agg[5] = {0.f, 0.f, 0.f, 0.f, 0.f};
    const float inv_scale = 0.125f;     // 1/sqrt(64)

    for (int l0 = 0; l0 < Lc; l0 += TL) {
        __syncthreads();
        // stage ctx tile: bf16 pairs (uint) -> fp32 LDS
        for (int idx = t; idx < TL * 128; idx += 256) {
            int r = idx >> 7, cp = idx & 127;
            int l = l0 + r;
            float v0 = 0.f, v1 = 0.f;
            if (l < Lc) {
                unsigned int u = *(const unsigned int*)&ctxb[(size_t)(b * Lc + l) * Hc + cp * 2];
                v0 = bf2f((unsigned short)(u & 0xffffu));
                v1 = bf2f((unsigned short)(u >> 16));
            }
            kv[r * STRIDE + cp * 2]     = v0;
            kv[r * STRIDE + cp * 2 + 1] = v1;
        }
        // te columns 256..271
        {
            int r = t >> 3;
            int l = l0 + r;
            float tc = (l < Lc) ? t_ctx[b * Lc + l] : 0.f;
            float lt = log1pf(fmaxf(tc, 0.f));
            float z = lt * fr + ph;
            kv[r * STRIDE + Hc + tf]      = __sinf(z);
            kv[r * STRIDE + Hc + Tc + tf] = __cosf(z);
        }
        __syncthreads();

        int l = l0 + ll;
        float acc = 0.f;
        {
            const float* kvr = kv + ll * STRIDE + half * 136;
            const float* qp  = qkl + wave * KINc + half * 136;
            #pragma unroll 8
            for (int cci = 0; cci < 136; ++cci) acc += kvr[cci] * qp[cci];
        }
        acc += __shfl_xor(acc, 32);

        bool valid = (l < Lc);
        float logit;
        if (valid) {
            bool msk = act_ctx[b * Lc + l] > 0;
            logit = msk ? acc * inv_scale : NEG_BIG;
        } else {
            logit = -INFINITY;
        }
        float tmax = logit;
        #pragma unroll
        for (int off = 16; off >= 1; off >>= 1) tmax = fmaxf(tmax, __shfl_xor(tmax, off));
        float mnew = fmaxf(m, tmax);
        float fac = __expf(m - mnew);
        float p = valid ? __expf(logit - mnew) : 0.f;
        float psum = p;
        #pragma unroll
        for (int off = 16; off >= 1; off >>= 1) psum += __shfl_xor(psum, off);
        s = s * fac + psum;
        m = mnew;
        #pragma unroll
        for (int k = 0; k < 5; ++k) agg[k] *= fac;
        for (int li = 0; li < TL; ++li) {
            float pl = __shfl(p, li);
            const float* kvr = kv + li * STRIDE;
            #pragma unroll
            for (int k = 0; k < 5; ++k) {
                int j = lane + 64 * k;
                if (j < KINc) agg[k] += pl * kvr[j];
            }
        }
    }
    float sinv = 1.f / s;
    #pragma unroll
    for (int k = 0; k < 5; ++k) {
        int j = lane + 64 * k;
        if (j < KINc) cagg[(size_t)b * QKW + wave * KINc + j] = agg[k] * sinv;
    }
}

// ---------------- post-attention: aggproj + h@Wres + LN1 + FF + LN2 -> h
__global__ __launch_bounds__(256) void k_post(const float* __restrict__ cagg,
                                              float* __restrict__ h,
                                              const float* __restrict__ Wv,
                                              const float* __restrict__ Wres,
                                              const float* __restrict__ bres,
                                              const float* __restrict__ Wff1,
                                              const float* __restrict__ bff1,
                                              const float* __restrict__ Wff2,
                                              const float* __restrict__ bff2,
                                              const float* __restrict__ g1,
                                              const float* __restrict__ beta1,
                                              const float* __restrict__ g2,
                                              const float* __restrict__ beta2,
                                              int layer) {
    constexpr int R = 4;
    int b0 = blockIdx.x * R;
    int t = threadIdx.x;
    int wave = t >> 6, lane = t & 63;
    __shared__ float hl[R * Hc];
    __shared__ float cg[R * QKW];
    __shared__ float z1[R * Hc];
    __shared__ float ffa[R * Hc];
    __shared__ float red[R][2];
    for (int idx = t; idx < R * Hc; idx += 256) hl[idx] = h[b0 * Hc + idx];
    for (int idx = t; idx < R * QKW; idx += 256) cg[idx] = cagg[(size_t)b0 * QKW + idx];
    __syncthreads();

    const float* WvL   = Wv   + (size_t)layer * KINc * Hc;
    const float* WresL = Wres + (size_t)layer * Hc * Hc;
    int hh = t >> 6;
    float acc[R];
    float bb = bres[layer * Hc + t];
    #pragma unroll
    for (int r = 0; r < R; ++r) acc[r] = bb;
    for (int j = 0; j < KINc; ++j) {
        float w = WvL[j * Hc + t];
        #pragma unroll
        for (int r = 0; r < R; ++r) acc[r] += cg[r * QKW + hh * KINc + j] * w;
    }
    for (int d = 0; d < Hc; ++d) {
        float w = WresL[d * Hc + t];
        #pragma unroll
        for (int r = 0; r < R; ++r) acc[r] += hl[r * Hc + d] * w;
    }
    // ---- LN1
    #pragma unroll
    for (int r = 0; r < R; ++r) z1[r * Hc + t] = acc[r];
    __syncthreads();
    {
        int r = wave;
        float v0 = z1[r * Hc + lane], v1 = z1[r * Hc + lane + 64];
        float v2 = z1[r * Hc + lane + 128], v3 = z1[r * Hc + lane + 192];
        float sm = v0 + v1 + v2 + v3;
        float sq = v0 * v0 + v1 * v1 + v2 * v2 + v3 * v3;
        #pragma unroll
        for (int off = 32; off >= 1; off >>= 1) { sm += __shfl_xor(sm, off); sq += __shfl_xor(sq, off); }
        if (lane == 0) {
            float mu = sm * (1.f / Hc);
            float var = sq * (1.f / Hc) - mu * mu;
            red[r][0] = mu;
            red[r][1] = rsqrtf(var + LN_EPS_V);
        }
    }
    __syncthreads();
    float z1v[R];
    float g1t = g1[layer * Hc + t], b1t = beta1[layer * Hc + t];
    #pragma unroll
    for (int r = 0; r < R; ++r) {
        z1v[r] = (acc[r] - red[r][0]) * red[r][1] * g1t + b1t;
        z1[r * Hc + t] = z1v[r];
    }
    __syncthreads();
    // ---- FF1
    const float* W1 = Wff1 + (size_t)layer * Hc * Hc;
    float f1[R];
    float bf1 = bff1[layer * Hc + t];
    #pragma unroll
    for (int r = 0; r < R; ++r) f1[r] = bf1;
    for (int d = 0; d < Hc; ++d) {
        float w = W1[d * Hc + t];
        #pragma unroll
        for (int r = 0; r < R; ++r) f1[r] += z1[r * Hc + d] * w;
    }
    #pragma unroll
    for (int r = 0; r < R; ++r) ffa[r * Hc + t] = fmaxf(f1[r], 0.f);
    __syncthreads();
    // ---- FF2 + residual
    const float* W2 = Wff2 + (size_t)layer * Hc * Hc;
    float y[R];
    float bf2 = bff2[layer * Hc + t];
    #pragma unroll
    for (int r = 0; r < R; ++r) y[r] = z1v[r] + bf2;
    for (int d = 0; d < Hc; ++d) {
        float w = W2[d * Hc + t];
        #pragma unroll
        for (int r = 0; r < R; ++r) y[r] += ffa[r * Hc + d] * w;
    }
    // ---- LN2 -> h
    __syncthreads();
    #pragma unroll
    for (int r = 0; r < R; ++r) z1[r * Hc + t] = y[r];
    __syncthreads();
    {
        int r = wave;
        float v0 = z1[r * Hc + lane], v1 = z1[r * Hc + lane + 64];
        float v2 = z1[r * Hc + lane + 128], v3 = z1[r * Hc + lane + 192];
        float sm = v0 + v1 + v2 + v3;
        float sq = v0 * v0 + v1 * v1 + v2 * v2 + v3 * v3;
        #pragma unroll
        for (int off = 32; off >= 1; off >>= 1) { sm += __shfl_xor(sm, off); sq += __shfl_xor(sq, off); }
        if (lane == 0) {
            float mu = sm * (1.f / Hc);
            float var = sq * (1.f / Hc) - mu * mu;
            red[r][0] = mu;
            red[r][1] = rsqrtf(var + LN_EPS_V);
        }
    }
    __syncthreads();
    float g2t = g2[layer * Hc + t], b2t = beta2[layer * Hc + t];
    #pragma unroll
    for (int r = 0; r < R; ++r)
        h[(b0 + r) * Hc + t] = (y[r] - red[r][0]) * red[r][1] * g2t + b2t;
}

// ---------------- head
__global__ __launch_bounds__(256) void k_head(const float* __restrict__ h,
                                              const float* __restrict__ W_ro,
                                              const float* __restrict__ b_ro,
                                              const float* __restrict__ W_cls,
                                              const float* __restrict__ b_cls,
                                              const float* __restrict__ W_dt,
                                              const float* __restrict__ b_dt,
                                              const float* __restrict__ W_rem,
                                              const float* __restrict__ b_rem,
                                              float* __restrict__ out) {
    constexpr int R = 8;
    int b0 = blockIdx.x * R;
    int t = threadIdx.x;
    int wave = t >> 6, lane = t & 63;
    __shared__ float hl[R * Hc], zl[R * Hc];
    __shared__ float wcls[Hc * Cc];
    __shared__ float wdt[Hc], wrem[Hc];
    for (int idx = t; idx < R * Hc; idx += 256) hl[idx] = h[b0 * Hc + idx];
    for (int idx = t; idx < Hc * Cc; idx += 256) wcls[idx] = W_cls[idx];
    wdt[t] = W_dt[t];
    wrem[t] = W_rem[t];
    __syncthreads();
    float acc[R];
    float br = b_ro[t];
    #pragma unroll
    for (int r = 0; r < R; ++r) acc[r] = br;
    for (int d = 0; d < Hc; ++d) {
        float w = W_ro[d * Hc + t];
        #pragma unroll
        for (int r = 0; r < R; ++r) acc[r] += hl[r * Hc + d] * w;
    }
    #pragma unroll
    for (int r = 0; r < R; ++r) zl[r * Hc + t] = fmaxf(acc[r], 0.f);
    __syncthreads();
    {
        int rr = t >> 5;
        int c = t & 31;
        float a = b_cls[c];
        for (int d = 0; d < Hc; ++d) a += zl[rr * Hc + d] * wcls[d * Cc + c];
        out[(size_t)(b0 + rr) * Cc + c] = a;
    }
    for (int rr = wave * 2; rr < wave * 2 + 2; ++rr) {
        float sd = 0.f, sr = 0.f;
        #pragma unroll
        for (int k2 = 0; k2 < 4; ++k2) {
            float zv = zl[rr * Hc + lane + 64 * k2];
            sd += zv * wdt[lane + 64 * k2];
            sr += zv * wrem[lane + 64 * k2];
        }
        #pragma unroll
        for (int off = 32; off >= 1; off >>= 1) { sd += __shfl_xor(sd, off); sr += __shfl_xor(sr, off); }
        if (lane == 0) {
            out[(size_t)Bc * Cc + b0 + rr]      = 1.f / (1.f + __expf(-(sd + b_dt[0])));
            out[(size_t)Bc * Cc + Bc + b0 + rr] = 1.f / (1.f + __expf(-(sr + b_rem[0])));
        }
    }
}

extern "C" void kernel_launch(void* const* d_in, const int* in_sizes, int n_in,
                              void* d_out, int out_size, void* d_ws, size_t ws_size,
                              hipStream_t stream) {
    const float* x_u      = (const float*)d_in[0];
    const float* x_ctx    = (const float*)d_in[1];
    const float* t_ctx    = (const float*)d_in[2];
    const int*   act_u    = (const int*)d_in[3];
    const int*   act_ctx  = (const int*)d_in[4];
    const float* emb      = (const float*)d_in[5];
    const float* W_in_self = (const float*)d_in[6];
    const float* b_in_self = (const float*)d_in[7];
    const float* W_in_ctx  = (const float*)d_in[8];
    const float* b_in_ctx  = (const float*)d_in[9];
    const float* freq  = (const float*)d_in[10];
    const float* phase = (const float*)d_in[11];
    const float* Wq    = (const float*)d_in[12];
    const float* Wk    = (const float*)d_in[13];
    const float* Wv    = (const float*)d_in[14];
    const float* Wres  = (const float*)d_in[15];
    const float* bres  = (const float*)d_in[16];
    const float* Wff1  = (const float*)d_in[17];
    const float* bff1  = (const float*)d_in[18];
    const float* Wff2  = (const float*)d_in[19];
    const float* bff2  = (const float*)d_in[20];
    const float* g1    = (const float*)d_in[21];
    const float* beta1 = (const float*)d_in[22];
    const float* g2    = (const float*)d_in[23];
    const float* beta2 = (const float*)d_in[24];
    const float* W_ro  = (const float*)d_in[25];
    const float* b_ro  = (const float*)d_in[26];
    const float* W_cls = (const float*)d_in[27];
    const float* b_cls = (const float*)d_in[28];
    const float* W_dt  = (const float*)d_in[29];
    const float* b_dt  = (const float*)d_in[30];
    const float* W_rem = (const float*)d_in[31];
    const float* b_rem = (const float*)d_in[32];

    float* ws   = (float*)d_ws;
    float* hbuf = ws;                                   // B*H
    float* wqk  = hbuf + (size_t)Bc * Hc;               // NL*H*QKW
    float* qk   = wqk  + (size_t)NLc * Hc * QKW;        // B*QKW
    float* cagg = qk   + (size_t)Bc * QKW;              // B*QKW
    unsigned short* ctxb = (unsigned short*)(cagg + (size_t)Bc * QKW); // B*L*H bf16
    unsigned short* wswz = ctxb + (size_t)Bc * Lc * Hc;                // 3*16*64*8 bf16
    size_t need_bytes = ((size_t)Bc * Hc + (size_t)NLc * Hc * QKW + 2 * (size_t)Bc * QKW) * 4
                        + ((size_t)Bc * Lc * Hc + 3 * 16 * 64 * 8) * 2;
    if (ws_size < need_bytes) return;

    float* out = (float*)d_out;

    k_prep_wswz<<<12, 256, 0, stream>>>(W_in_ctx, wswz);
    k_wqk<<<NLc * Hc, 256, 0, stream>>>(Wq, Wk, wqk);
    k_h0<<<Bc / 16, 256, 0, stream>>>(x_u, act_u, emb, W_in_self, b_in_self, hbuf);
    k_ctx_mfma<<<(Bc * Lc) / 64, 256, 0, stream>>>(x_ctx, act_ctx, emb, wswz, b_in_ctx, ctxb);

    for (int i = 0; i < NLc; ++i) {
        k_qk<<<640, 256, 0, stream>>>(hbuf, wqk + (size_t)i * Hc * QKW, qk);
        k_att<<<Bc, 256, 0, stream>>>(ctxb, qk, t_ctx, act_ctx, freq, phase, cagg, i);
        k_post<<<Bc / 4, 256, 0, stream>>>(cagg, hbuf, Wv, Wres, bres,
                                           Wff1, bff1, Wff2, bff2,
                                           g1, beta1, g2, beta2, i);
    }
    k_head<<<Bc / 8, 256, 0, stream>>>(hbuf, W_ro, b_ro, W_cls, b_cls,
                                       W_dt, b_dt, W_rem, b_rem, out);
}

// Round 3
// 453.254 us; speedup vs baseline: 2.4743x; 1.3350x over previous
//
#include <hip/hip_runtime.h>
#include <math.h>

namespace {
constexpr int Bc   = 1024;
constexpr int Lc   = 200;
constexpr int Dc   = 64;
constexpr int Ec   = 32;
constexpr int Pc   = 96;    // D+E
constexpr int Hc   = 256;
constexpr int Tc   = 8;
constexpr int NLc  = 3;
constexpr int KINc = 272;   // H+2T
constexpr int DHc  = 64;
constexpr int Cc   = 32;
constexpr int QKW  = 1088;  // NH*KIN
constexpr int QS   = 113;   // per-head query slots: 96 xc + 16 te + 1 bias-const
constexpr int Q4   = 452;   // 4*QS
constexpr int CG   = 112;   // per-head agg cols: 96 xc-agg + 16 te-agg
constexpr int CGW  = 448;   // 4*CG
constexpr float LN_EPS_V = 1e-5f;
constexpr float NEG_BIG  = -1e9f;

typedef __attribute__((ext_vector_type(8))) short bf16x8;
typedef __attribute__((ext_vector_type(4))) float f32x4;

__device__ __forceinline__ unsigned short f2bf(float f) {
    union { float f; unsigned int u; } v; v.f = f;
    unsigned int u = v.u;
    unsigned int r = (u + 0x7fffu + ((u >> 16) & 1u)) >> 16;
    return (unsigned short)r;
}
__device__ __forceinline__ float bf2f(unsigned short us) {
    union { unsigned int u; float f; } v; v.u = ((unsigned int)us) << 16;
    return v.f;
}
}

// ---------------- wqk[i][e][hh*272+j] = sum_d Wq[i,e,hh*64+d] * Wk[i,j,hh*64+d]
__global__ __launch_bounds__(256) void k_wqk(const float* __restrict__ Wq,
                                             const float* __restrict__ Wk,
                                             float* __restrict__ wqk) {
    int blk = blockIdx.x;           // NLc*Hc blocks
    int i = blk >> 8;
    int e = blk & 255;
    int t = threadIdx.x;
    __shared__ float qrow[Hc];
    qrow[t] = Wq[i * Hc * Hc + e * Hc + t];
    __syncthreads();
    const float* wkL = Wk + (size_t)i * KINc * Hc;
    for (int c = t; c < QKW; c += 256) {
        int hh = c / KINc;
        int j  = c - hh * KINc;
        const float* wkr = wkL + j * Hc + hh * DHc;
        const float* qr  = qrow + hh * DHc;
        float acc = 0.f;
        #pragma unroll
        for (int d = 0; d < DHc; ++d) acc += qr[d] * wkr[d];
        wqk[(size_t)i * Hc * QKW + e * QKW + c] = acc;
    }
}

// ---------------- Wbig[i][e][h*113 + r]:
//  r<96:     0.125 * sum_{c<256} wqk[i,e,h*272+c] * W_in_ctx[r*256+c]
//  96..111:  0.125 * wqk[i,e,h*272+256+(r-96)]
//  r==112:   0.125 * sum_c wqk[i,e,h*272+c] * b_in_ctx[c]
__global__ __launch_bounds__(256) void k_wbig(const float* __restrict__ wqk,
                                              const float* __restrict__ W_in_ctx,
                                              const float* __restrict__ b_in_ctx,
                                              float* __restrict__ wbig) {
    int blk = blockIdx.x;           // NLc*Hc blocks
    int i = blk >> 8;
    int e = blk & 255;
    int t = threadIdx.x;
    __shared__ float wq[QKW];
    __shared__ float bl[Hc];
    for (int idx = t; idx < QKW; idx += 256) wq[idx] = wqk[(size_t)i * Hc * QKW + e * QKW + idx];
    bl[t] = b_in_ctx[t];
    __syncthreads();
    for (int slot = t; slot < Q4; slot += 256) {
        int h = slot / QS;
        int r = slot - h * QS;
        const float* wqh = wq + h * KINc;
        float acc = 0.f;
        if (r < 96) {
            const float* wr = W_in_ctx + r * Hc;
            for (int c = 0; c < Hc; ++c) acc += wqh[c] * wr[c];
        } else if (r < 112) {
            acc = wqh[256 + (r - 96)];
        } else {
            for (int c = 0; c < Hc; ++c) acc += wqh[c] * bl[c];
        }
        wbig[(size_t)(i * Hc + e) * Q4 + slot] = 0.125f * acc;
    }
}

// ---------------- wvp2[i][j][t], j in [0,113):
//  j<96:    sum_{c<256} W_in_ctx[j*256+c] * Wv[i,c,t]
//  96..111: Wv[i, 256+(j-96), t]
//  j==112:  sum_c b_in_ctx[c] * Wv[i,c,t]
__global__ __launch_bounds__(256) void k_wvp(const float* __restrict__ W_in_ctx,
                                             const float* __restrict__ b_in_ctx,
                                             const float* __restrict__ Wv,
                                             float* __restrict__ wvp2) {
    int blk = blockIdx.x;           // NLc*113 blocks
    int i = blk / QS;
    int j = blk - i * QS;
    int t = threadIdx.x;
    __shared__ float wrow[Hc];
    if (j < 96)       wrow[t] = W_in_ctx[j * Hc + t];
    else if (j == 112) wrow[t] = b_in_ctx[t];
    __syncthreads();
    const float* WvL = Wv + (size_t)i * KINc * Hc;
    float acc;
    if (j >= 96 && j < 112) {
        acc = WvL[(256 + (j - 96)) * Hc + t];
    } else {
        acc = 0.f;
        for (int c = 0; c < Hc; ++c) acc += wrow[c] * WvL[c * Hc + t];
    }
    wvp2[(size_t)blk * Hc + t] = acc;
}

// ---------------- h0 = [x_u, emb[act_u]] @ W_in_self + b
__global__ __launch_bounds__(256) void k_h0(const float* __restrict__ x_u,
                                            const int* __restrict__ act_u,
                                            const float* __restrict__ emb,
                                            const float* __restrict__ W,
                                            const float* __restrict__ bias,
                                            float* __restrict__ h) {
    constexpr int R = 16;
    int b0 = blockIdx.x * R;
    int t = threadIdx.x;
    __shared__ float xu[R * Pc];
    for (int idx = t; idx < R * Pc; idx += 256) {
        int r = idx / Pc, j = idx - r * Pc;
        int b = b0 + r;
        float v;
        if (j < Dc) v = x_u[b * Dc + j];
        else        v = emb[act_u[b] * Ec + (j - Dc)];
        xu[idx] = v;
    }
    __syncthreads();
    float acc[R];
    float bb = bias[t];
    #pragma unroll
    for (int r = 0; r < R; ++r) acc[r] = bb;
    for (int j = 0; j < Pc; ++j) {
        float w = W[j * Hc + t];
        #pragma unroll
        for (int r = 0; r < R; ++r) acc[r] += xu[r * Pc + j] * w;
    }
    #pragma unroll
    for (int r = 0; r < R; ++r) h[(b0 + r) * Hc + t] = acc[r];
}

// ---------------- qk2 = h @ Wbig[i]   (1024x256 @ 256x452)
__global__ __launch_bounds__(256) void k_qk2(const float* __restrict__ h,
                                             const float* __restrict__ wbig_l,
                                             float* __restrict__ qk2) {
    constexpr int R = 8;
    int rb = blockIdx.x & 127;
    int cb = blockIdx.x >> 7;       // 0..1
    int b0 = rb * R;
    int t = threadIdx.x;
    int c = cb * 256 + t;
    __shared__ float hl[R * Hc];
    for (int idx = t; idx < R * Hc; idx += 256) hl[idx] = h[b0 * Hc + idx];
    __syncthreads();
    if (c >= Q4) return;
    float acc[R];
    #pragma unroll
    for (int r = 0; r < R; ++r) acc[r] = 0.f;
    for (int e = 0; e < Hc; ++e) {
        float w = wbig_l[(size_t)e * Q4 + c];
        #pragma unroll
        for (int r = 0; r < R; ++r) acc[r] += hl[r * Hc + e] * w;
    }
    #pragma unroll
    for (int r = 0; r < R; ++r) qk2[(size_t)(b0 + r) * Q4 + c] = acc[r];
}

// ---------------- fused attention over xc/te only. One block per b, 4 waves.
// xt[208][128] bf16: cols 0:64 x_ctx, 64:96 emb, 96:104 sin, 104:112 cos,
// col 112 = 1.0 (bias slot), 113..127 = 0. 16B col-blocks XOR-swizzled by (l&7).
// logits: MFMA 16x16x32 bf16, K=128. softmax exact (2-phase). PV scalar.
// out: cagg[b][h*112 + j] = sum_l p[h,l] * xt[l][j]  (j<112, p normalized)
__global__ __launch_bounds__(256) void k_att(const float* __restrict__ x_ctx,
                                             const int* __restrict__ act_ctx,
                                             const float* __restrict__ emb,
                                             const float* __restrict__ t_ctx,
                                             const float* __restrict__ freq,
                                             const float* __restrict__ phase,
                                             const float* __restrict__ qk2,
                                             float* __restrict__ cagg, int layer) {
    __shared__ unsigned short xt[208 * 128];
    __shared__ float S[4][208];
    __shared__ float P[208][4];
    __shared__ float qks[Q4];
    __shared__ float cmb[4][CGW];
    int b = blockIdx.x;
    int t = threadIdx.x;
    int wv = t >> 6, lane = t & 63;

    for (int idx = t; idx < Q4; idx += 256) qks[idx] = qk2[(size_t)b * Q4 + idx];

    // ---- stage xt
    const float* xrow = x_ctx + (size_t)b * Lc * Dc;
    for (int idx = t; idx < Lc * 16; idx += 256) {
        int l  = idx >> 4;
        int c8 = idx & 15;
        unsigned short v[8];
        if (c8 < 8) {
            const float* s = xrow + l * Dc + c8 * 8;
            float4 a = *(const float4*)s;
            float4 bq = *(const float4*)(s + 4);
            v[0]=f2bf(a.x); v[1]=f2bf(a.y); v[2]=f2bf(a.z); v[3]=f2bf(a.w);
            v[4]=f2bf(bq.x); v[5]=f2bf(bq.y); v[6]=f2bf(bq.z); v[7]=f2bf(bq.w);
        } else if (c8 < 12) {
            int a = act_ctx[b * Lc + l];
            const float* s = emb + a * Ec + (c8 - 8) * 8;
            float4 e0 = *(const float4*)s;
            float4 e1 = *(const float4*)(s + 4);
            v[0]=f2bf(e0.x); v[1]=f2bf(e0.y); v[2]=f2bf(e0.z); v[3]=f2bf(e0.w);
            v[4]=f2bf(e1.x); v[5]=f2bf(e1.y); v[6]=f2bf(e1.z); v[7]=f2bf(e1.w);
        } else if (c8 < 14) {
            float lt = log1pf(fmaxf(t_ctx[b * Lc + l], 0.f));
            #pragma unroll
            for (int j = 0; j < 8; ++j) {
                float z = lt * freq[layer * Tc + j] + phase[layer * Tc + j];
                v[j] = f2bf((c8 == 12) ? __sinf(z) : __cosf(z));
            }
        } else if (c8 == 14) {
            v[0] = f2bf(1.0f);
            #pragma unroll
            for (int j = 1; j < 8; ++j) v[j] = 0;
        } else {
            #pragma unroll
            for (int j = 0; j < 8; ++j) v[j] = 0;
        }
        int s = c8 ^ (l & 7);
        *(uint4*)&xt[l * 128 + s * 8] = *(const uint4*)v;
    }
    __syncthreads();

    // ---- B-fragments (query), held in VGPRs
    bf16x8 bfr[4];
    {
        int h  = lane & 15;
        int kb = (lane >> 4) * 8;
        #pragma unroll
        for (int kk = 0; kk < 4; ++kk) {
            unsigned short tmp[8];
            #pragma unroll
            for (int j = 0; j < 8; ++j) {
                int k = kk * 32 + kb + j;
                float val = (h < 4 && k < QS) ? qks[h * QS + k] : 0.f;
                tmp[j] = f2bf(val);
            }
            bfr[kk] = *(const bf16x8*)tmp;
        }
    }

    // ---- logits via MFMA: S[h][l]
    for (int tile = wv; tile < 13; tile += 4) {
        int r = tile * 16 + (lane & 15);
        f32x4 acc = {0.f, 0.f, 0.f, 0.f};
        #pragma unroll
        for (int kk = 0; kk < 4; ++kk) {
            int s = (kk * 4 + (lane >> 4)) ^ (r & 7);
            bf16x8 a = *(const bf16x8*)&xt[r * 128 + s * 8];
            acc = __builtin_amdgcn_mfma_f32_16x16x32_bf16(a, bfr[kk], acc, 0, 0, 0);
        }
        int h = lane & 15;
        if (h < 4) {
            int rb = tile * 16 + (lane >> 4) * 4;
            #pragma unroll
            for (int q = 0; q < 4; ++q) S[h][rb + q] = acc[q];
        }
    }
    __syncthreads();

    // ---- softmax, wave = head (exact, scale already folded into query)
    {
        int h = wv;
        float lv[4];
        #pragma unroll
        for (int k = 0; k < 4; ++k) {
            int l = lane + 64 * k;
            if (l < Lc) lv[k] = (act_ctx[b * Lc + l] > 0) ? S[h][l] : NEG_BIG;
            else        lv[k] = -INFINITY;
        }
        float m = fmaxf(fmaxf(lv[0], lv[1]), fmaxf(lv[2], lv[3]));
        #pragma unroll
        for (int off = 32; off >= 1; off >>= 1) m = fmaxf(m, __shfl_xor(m, off));
        float p[4];
        float ssum = 0.f;
        #pragma unroll
        for (int k = 0; k < 4; ++k) {
            int l = lane + 64 * k;
            p[k] = (l < Lc) ? __expf(lv[k] - m) : 0.f;
            ssum += p[k];
        }
        #pragma unroll
        for (int off = 32; off >= 1; off >>= 1) ssum += __shfl_xor(ssum, off);
        float sinv = 1.f / ssum;
        #pragma unroll
        for (int k = 0; k < 4; ++k) {
            int l = lane + 64 * k;
            if (l < Lc) P[l][h] = p[k] * sinv;
        }
    }
    __syncthreads();

    // ---- PV: wave handles 50 l's; lane handles col pair (2*lane, 2*lane+1)
    float ag[4][2] = {{0.f,0.f},{0.f,0.f},{0.f,0.f},{0.f,0.f}};
    {
        int l0 = wv * 50;
        int c0 = lane * 2;
        for (int li = 0; li < 50; ++li) {
            int l = l0 + li;
            f32x4 p4 = *(const f32x4*)&P[l][0];
            if (lane < 56) {
                int s = (c0 >> 3) ^ (l & 7);
                unsigned int u = *(const unsigned int*)&xt[l * 128 + s * 8 + (c0 & 7)];
                float x0 = bf2f((unsigned short)(u & 0xffffu));
                float x1 = bf2f((unsigned short)(u >> 16));
                #pragma unroll
                for (int h = 0; h < 4; ++h) {
                    ag[h][0] += p4[h] * x0;
                    ag[h][1] += p4[h] * x1;
                }
            }
        }
    }
    if (lane < 56) {
        #pragma unroll
        for (int h = 0; h < 4; ++h) {
            cmb[wv][h * CG + lane * 2]     = ag[h][0];
            cmb[wv][h * CG + lane * 2 + 1] = ag[h][1];
        }
    }
    __syncthreads();
    for (int o = t; o < CGW; o += 256) {
        float sm = cmb[0][o] + cmb[1][o] + cmb[2][o] + cmb[3][o];
        cagg[(size_t)b * CGW + o] = sm;
    }
}

// ---------------- post-attention: aggproj(112) + h@Wres + LN1 + FF + LN2 -> h
__global__ __launch_bounds__(256) void k_post(const float* __restrict__ cagg,
                                              float* __restrict__ h,
                                              const float* __restrict__ wvp2,
                                              const float* __restrict__ Wres,
                                              const float* __restrict__ bres,
                                              const float* __restrict__ Wff1,
                                              const float* __restrict__ bff1,
                                              const float* __restrict__ Wff2,
                                              const float* __restrict__ bff2,
                                              const float* __restrict__ g1,
                                              const float* __restrict__ beta1,
                                              const float* __restrict__ g2,
                                              const float* __restrict__ beta2,
                                              int layer) {
    constexpr int R = 4;
    int b0 = blockIdx.x * R;
    int t = threadIdx.x;
    int wave = t >> 6, lane = t & 63;
    __shared__ float hl[R * Hc];
    __shared__ float cg[R * CGW];
    __shared__ float z1[R * Hc];
    __shared__ float ffa[R * Hc];
    __shared__ float red[R][2];
    for (int idx = t; idx < R * Hc; idx += 256) hl[idx] = h[b0 * Hc + idx];
    for (int idx = t; idx < R * CGW; idx += 256) cg[idx] = cagg[(size_t)b0 * CGW + idx];
    __syncthreads();

    const float* wvpL  = wvp2 + (size_t)layer * QS * Hc;
    const float* WresL = Wres + (size_t)layer * Hc * Hc;
    int hh = t >> 6;
    float acc[R];
    float bb = bres[layer * Hc + t] + wvpL[112 * Hc + t];
    #pragma unroll
    for (int r = 0; r < R; ++r) acc[r] = bb;
    for (int j = 0; j < CG; ++j) {
        float w = wvpL[j * Hc + t];
        #pragma unroll
        for (int r = 0; r < R; ++r) acc[r] += cg[r * CGW + hh * CG + j] * w;
    }
    for (int d = 0; d < Hc; ++d) {
        float w = WresL[d * Hc + t];
        #pragma unroll
        for (int r = 0; r < R; ++r) acc[r] += hl[r * Hc + d] * w;
    }
    // ---- LN1
    #pragma unroll
    for (int r = 0; r < R; ++r) z1[r * Hc + t] = acc[r];
    __syncthreads();
    {
        int r = wave;
        float v0 = z1[r * Hc + lane], v1 = z1[r * Hc + lane + 64];
        float v2 = z1[r * Hc + lane + 128], v3 = z1[r * Hc + lane + 192];
        float sm = v0 + v1 + v2 + v3;
        float sq = v0 * v0 + v1 * v1 + v2 * v2 + v3 * v3;
        #pragma unroll
        for (int off = 32; off >= 1; off >>= 1) { sm += __shfl_xor(sm, off); sq += __shfl_xor(sq, off); }
        if (lane == 0) {
            float mu = sm * (1.f / Hc);
            float var = sq * (1.f / Hc) - mu * mu;
            red[r][0] = mu;
            red[r][1] = rsqrtf(var + LN_EPS_V);
        }
    }
    __syncthreads();
    float z1v[R];
    float g1t = g1[layer * Hc + t], b1t = beta1[layer * Hc + t];
    #pragma unroll
    for (int r = 0; r < R; ++r) {
        z1v[r] = (acc[r] - red[r][0]) * red[r][1] * g1t + b1t;
        z1[r * Hc + t] = z1v[r];
    }
    __syncthreads();
    // ---- FF1
    const float* W1 = Wff1 + (size_t)layer * Hc * Hc;
    float f1[R];
    float bf1 = bff1[layer * Hc + t];
    #pragma unroll
    for (int r = 0; r < R; ++r) f1[r] = bf1;
    for (int d = 0; d < Hc; ++d) {
        float w = W1[d * Hc + t];
        #pragma unroll
        for (int r = 0; r < R; ++r) f1[r] += z1[r * Hc + d] * w;
    }
    #pragma unroll
    for (int r = 0; r < R; ++r) ffa[r * Hc + t] = fmaxf(f1[r], 0.f);
    __syncthreads();
    // ---- FF2 + residual
    const float* W2 = Wff2 + (size_t)layer * Hc * Hc;
    float y[R];
    float bf2 = bff2[layer * Hc + t];
    #pragma unroll
    for (int r = 0; r < R; ++r) y[r] = z1v[r] + bf2;
    for (int d = 0; d < Hc; ++d) {
        float w = W2[d * Hc + t];
        #pragma unroll
        for (int r = 0; r < R; ++r) y[r] += ffa[r * Hc + d] * w;
    }
    // ---- LN2 -> h
    __syncthreads();
    #pragma unroll
    for (int r = 0; r < R; ++r) z1[r * Hc + t] = y[r];
    __syncthreads();
    {
        int r = wave;
        float v0 = z1[r * Hc + lane], v1 = z1[r * Hc + lane + 64];
        float v2 = z1[r * Hc + lane + 128], v3 = z1[r * Hc + lane + 192];
        float sm = v0 + v1 + v2 + v3;
        float sq = v0 * v0 + v1 * v1 + v2 * v2 + v3 * v3;
        #pragma unroll
        for (int off = 32; off >= 1; off >>= 1) { sm += __shfl_xor(sm, off); sq += __shfl_xor(sq, off); }
        if (lane == 0) {
            float mu = sm * (1.f / Hc);
            float var = sq * (1.f / Hc) - mu * mu;
            red[r][0] = mu;
            red[r][1] = rsqrtf(var + LN_EPS_V);
        }
    }
    __syncthreads();
    float g2t = g2[layer * Hc + t], b2t = beta2[layer * Hc + t];
    #pragma unroll
    for (int r = 0; r < R; ++r)
        h[(b0 + r) * Hc + t] = (y[r] - red[r][0]) * red[r][1] * g2t + b2t;
}

// ---------------- head
__global__ __launch_bounds__(256) void k_head(const float* __restrict__ h,
                                              const float* __restrict__ W_ro,
                                              const float* __restrict__ b_ro,
                                              const float* __restrict__ W_cls,
                                              const float* __restrict__ b_cls,
                                              const float* __restrict__ W_dt,
                                              const float* __restrict__ b_dt,
                                              const float* __restrict__ W_rem,
                                              const float* __restrict__ b_rem,
                                              float* __restrict__ out) {
    constexpr int R = 8;
    int b0 = blockIdx.x * R;
    int t = threadIdx.x;
    int wave = t >> 6, lane = t & 63;
    __shared__ float hl[R * Hc], zl[R * Hc];
    __shared__ float wcls[Hc * Cc];
    __shared__ float wdt[Hc], wrem[Hc];
    for (int idx = t; idx < R * Hc; idx += 256) hl[idx] = h[b0 * Hc + idx];
    for (int idx = t; idx < Hc * Cc; idx += 256) wcls[idx] = W_cls[idx];
    wdt[t] = W_dt[t];
    wrem[t] = W_rem[t];
    __syncthreads();
    float acc[R];
    float br = b_ro[t];
    #pragma unroll
    for (int r = 0; r < R; ++r) acc[r] = br;
    for (int d = 0; d < Hc; ++d) {
        float w = W_ro[d * Hc + t];
        #pragma unroll
        for (int r = 0; r < R; ++r) acc[r] += hl[r * Hc + d] * w;
    }
    #pragma unroll
    for (int r = 0; r < R; ++r) zl[r * Hc + t] = fmaxf(acc[r], 0.f);
    __syncthreads();
    {
        int rr = t >> 5;
        int c = t & 31;
        float a = b_cls[c];
        for (int d = 0; d < Hc; ++d) a += zl[rr * Hc + d] * wcls[d * Cc + c];
        out[(size_t)(b0 + rr) * Cc + c] = a;
    }
    for (int rr = wave * 2; rr < wave * 2 + 2; ++rr) {
        float sd = 0.f, sr = 0.f;
        #pragma unroll
        for (int k2 = 0; k2 < 4; ++k2) {
            float zv = zl[rr * Hc + lane + 64 * k2];
            sd += zv * wdt[lane + 64 * k2];
            sr += zv * wrem[lane + 64 * k2];
        }
        #pragma unroll
        for (int off = 32; off >= 1; off >>= 1) { sd += __shfl_xor(sd, off); sr += __shfl_xor(sr, off); }
        if (lane == 0) {
            out[(size_t)Bc * Cc + b0 + rr]      = 1.f / (1.f + __expf(-(sd + b_dt[0])));
            out[(size_t)Bc * Cc + Bc + b0 + rr] = 1.f / (1.f + __expf(-(sr + b_rem[0])));
        }
    }
}

extern "C" void kernel_launch(void* const* d_in, const int* in_sizes, int n_in,
                              void* d_out, int out_size, void* d_ws, size_t ws_size,
                              hipStream_t stream) {
    const float* x_u      = (const float*)d_in[0];
    const float* x_ctx    = (const float*)d_in[1];
    const float* t_ctx    = (const float*)d_in[2];
    const int*   act_u    = (const int*)d_in[3];
    const int*   act_ctx  = (const int*)d_in[4];
    const float* emb      = (const float*)d_in[5];
    const float* W_in_self = (const float*)d_in[6];
    const float* b_in_self = (const float*)d_in[7];
    const float* W_in_ctx  = (const float*)d_in[8];
    const float* b_in_ctx  = (const float*)d_in[9];
    const float* freq  = (const float*)d_in[10];
    const float* phase = (const float*)d_in[11];
    const float* Wq    = (const float*)d_in[12];
    const float* Wk    = (const float*)d_in[13];
    const float* Wv    = (const float*)d_in[14];
    const float* Wres  = (const float*)d_in[15];
    const float* bres  = (const float*)d_in[16];
    const float* Wff1  = (const float*)d_in[17];
    const float* bff1  = (const float*)d_in[18];
    const float* Wff2  = (const float*)d_in[19];
    const float* bff2  = (const float*)d_in[20];
    const float* g1    = (const float*)d_in[21];
    const float* beta1 = (const float*)d_in[22];
    const float* g2    = (const float*)d_in[23];
    const float* beta2 = (const float*)d_in[24];
    const float* W_ro  = (const float*)d_in[25];
    const float* b_ro  = (const float*)d_in[26];
    const float* W_cls = (const float*)d_in[27];
    const float* b_cls = (const float*)d_in[28];
    const float* W_dt  = (const float*)d_in[29];
    const float* b_dt  = (const float*)d_in[30];
    const float* W_rem = (const float*)d_in[31];
    const float* b_rem = (const float*)d_in[32];

    float* ws    = (float*)d_ws;
    float* hbuf  = ws;                                    // B*H
    float* wqk   = hbuf  + (size_t)Bc * Hc;               // NL*H*QKW
    float* wbig  = wqk   + (size_t)NLc * Hc * QKW;        // NL*H*Q4
    float* qk2   = wbig  + (size_t)NLc * Hc * Q4;         // B*Q4
    float* cagg2 = qk2   + (size_t)Bc * Q4;               // B*CGW
    float* wvp2  = cagg2 + (size_t)Bc * CGW;              // NL*QS*H
    size_t need = ((size_t)Bc * Hc + (size_t)NLc * Hc * QKW + (size_t)NLc * Hc * Q4
                  + (size_t)Bc * Q4 + (size_t)Bc * CGW + (size_t)NLc * QS * Hc) * sizeof(float);
    if (ws_size < need) return;

    float* out = (float*)d_out;

    k_wqk<<<NLc * Hc, 256, 0, stream>>>(Wq, Wk, wqk);
    k_wbig<<<NLc * Hc, 256, 0, stream>>>(wqk, W_in_ctx, b_in_ctx, wbig);
    k_wvp<<<NLc * QS, 256, 0, stream>>>(W_in_ctx, b_in_ctx, Wv, wvp2);
    k_h0<<<Bc / 16, 256, 0, stream>>>(x_u, act_u, emb, W_in_self, b_in_self, hbuf);

    for (int i = 0; i < NLc; ++i) {
        k_qk2<<<256, 256, 0, stream>>>(hbuf, wbig + (size_t)i * Hc * Q4, qk2);
        k_att<<<Bc, 256, 0, stream>>>(x_ctx, act_ctx, emb, t_ctx, freq, phase, qk2, cagg2, i);
        k_post<<<Bc / 4, 256, 0, stream>>>(cagg2, hbuf, wvp2, Wres, bres,
                                           Wff1, bff1, Wff2, bff2,
                                           g1, beta1, g2, beta2, i);
    }
    k_head<<<Bc / 8, 256, 0, stream>>>(hbuf, W_ro, b_ro, W_cls, b_cls,
                                       W_dt, b_dt, W_rem, b_rem, out);
}

// Round 4
// 423.416 us; speedup vs baseline: 2.6487x; 1.0705x over previous
//
#include <hip/hip_runtime.h>
#include <math.h>

namespace {
constexpr int Bc   = 1024;
constexpr int Lc   = 200;
constexpr int Dc   = 64;
constexpr int Ec   = 32;
constexpr int Pc   = 96;    // D+E
constexpr int Hc   = 256;
constexpr int Tc   = 8;
constexpr int NLc  = 3;
constexpr int KINc = 272;   // H+2T
constexpr int DHc  = 64;
constexpr int Cc   = 32;
constexpr int QKW  = 1088;  // NH*KIN
constexpr int QS   = 113;   // per-head query slots: 96 xc + 16 te + 1 bias-const
constexpr int Q4   = 452;   // 4*QS
constexpr int CG   = 112;   // per-head agg cols: 96 xc-agg + 16 te-agg
constexpr int CGW  = 448;   // 4*CG
constexpr int XROWS = Bc * Lc + 8;   // xtb rows (pad for r<=207 overrun)
constexpr int TEBS  = Bc * Lc + 8;   // per-layer teb rows
constexpr float LN_EPS_V = 1e-5f;
constexpr float NEG_BIG  = -1e9f;

typedef __attribute__((ext_vector_type(8))) short bf16x8;
typedef __attribute__((ext_vector_type(4))) float f32x4;

__device__ __forceinline__ unsigned short f2bf(float f) {
    union { float f; unsigned int u; } v; v.f = f;
    unsigned int u = v.u;
    unsigned int r = (u + 0x7fffu + ((u >> 16) & 1u)) >> 16;
    return (unsigned short)r;
}
}

// ---------------- wqk[i][e][hh*272+j] = sum_d Wq[i,e,hh*64+d] * Wk[i,j,hh*64+d]
__global__ __launch_bounds__(256) void k_wqk(const float* __restrict__ Wq,
                                             const float* __restrict__ Wk,
                                             float* __restrict__ wqk) {
    int blk = blockIdx.x;           // NLc*Hc blocks
    int i = blk >> 8;
    int e = blk & 255;
    int t = threadIdx.x;
    __shared__ float qrow[Hc];
    qrow[t] = Wq[i * Hc * Hc + e * Hc + t];
    __syncthreads();
    const float* wkL = Wk + (size_t)i * KINc * Hc;
    for (int c = t; c < QKW; c += 256) {
        int hh = c / KINc;
        int j  = c - hh * KINc;
        const float* wkr = wkL + j * Hc + hh * DHc;
        const float* qr  = qrow + hh * DHc;
        float acc = 0.f;
        #pragma unroll
        for (int d = 0; d < DHc; ++d) acc += qr[d] * wkr[d];
        wqk[(size_t)i * Hc * QKW + e * QKW + c] = acc;
    }
}

// ---------------- Wbig[i][e][h*113 + r]
__global__ __launch_bounds__(256) void k_wbig(const float* __restrict__ wqk,
                                              const float* __restrict__ W_in_ctx,
                                              const float* __restrict__ b_in_ctx,
                                              float* __restrict__ wbig) {
    int blk = blockIdx.x;           // NLc*Hc blocks
    int i = blk >> 8;
    int e = blk & 255;
    int t = threadIdx.x;
    __shared__ float wq[QKW];
    __shared__ float bl[Hc];
    for (int idx = t; idx < QKW; idx += 256) wq[idx] = wqk[(size_t)i * Hc * QKW + e * QKW + idx];
    bl[t] = b_in_ctx[t];
    __syncthreads();
    for (int slot = t; slot < Q4; slot += 256) {
        int h = slot / QS;
        int r = slot - h * QS;
        const float* wqh = wq + h * KINc;
        float acc = 0.f;
        if (r < 96) {
            const float* wr = W_in_ctx + r * Hc;
            for (int c = 0; c < Hc; ++c) acc += wqh[c] * wr[c];
        } else if (r < 112) {
            acc = wqh[256 + (r - 96)];
        } else {
            for (int c = 0; c < Hc; ++c) acc += wqh[c] * bl[c];
        }
        wbig[(size_t)(i * Hc + e) * Q4 + slot] = 0.125f * acc;
    }
}

// ---------------- wvp2[i][j][t]
__global__ __launch_bounds__(256) void k_wvp(const float* __restrict__ W_in_ctx,
                                             const float* __restrict__ b_in_ctx,
                                             const float* __restrict__ Wv,
                                             float* __restrict__ wvp2) {
    int blk = blockIdx.x;           // NLc*113 blocks
    int i = blk / QS;
    int j = blk - i * QS;
    int t = threadIdx.x;
    __shared__ float wrow[Hc];
    if (j < 96)       wrow[t] = W_in_ctx[j * Hc + t];
    else if (j == 112) wrow[t] = b_in_ctx[t];
    __syncthreads();
    const float* WvL = Wv + (size_t)i * KINc * Hc;
    float acc;
    if (j >= 96 && j < 112) {
        acc = WvL[(256 + (j - 96)) * Hc + t];
    } else {
        acc = 0.f;
        for (int c = 0; c < Hc; ++c) acc += wrow[c] * WvL[c * Hc + t];
    }
    wvp2[(size_t)blk * Hc + t] = acc;
}

// ---------------- h0 = [x_u, emb[act_u]] @ W_in_self + b
__global__ __launch_bounds__(256) void k_h0(const float* __restrict__ x_u,
                                            const int* __restrict__ act_u,
                                            const float* __restrict__ emb,
                                            const float* __restrict__ W,
                                            const float* __restrict__ bias,
                                            float* __restrict__ h) {
    constexpr int R = 16;
    int b0 = blockIdx.x * R;
    int t = threadIdx.x;
    __shared__ float xu[R * Pc];
    for (int idx = t; idx < R * Pc; idx += 256) {
        int r = idx / Pc, j = idx - r * Pc;
        int b = b0 + r;
        float v;
        if (j < Dc) v = x_u[b * Dc + j];
        else        v = emb[act_u[b] * Ec + (j - Dc)];
        xu[idx] = v;
    }
    __syncthreads();
    float acc[R];
    float bb = bias[t];
    #pragma unroll
    for (int r = 0; r < R; ++r) acc[r] = bb;
    for (int j = 0; j < Pc; ++j) {
        float w = W[j * Hc + t];
        #pragma unroll
        for (int r = 0; r < R; ++r) acc[r] += xu[r * Pc + j] * w;
    }
    #pragma unroll
    for (int r = 0; r < R; ++r) h[(b0 + r) * Hc + t] = acc[r];
}

// ---------------- prep: xtb[b][l][96], xtTb[b][96][224], teb[i][b][l][16], teTb[i][b][16][224]
__global__ __launch_bounds__(256) void k_prep(const float* __restrict__ x_ctx,
                                              const int* __restrict__ act_ctx,
                                              const float* __restrict__ emb,
                                              const float* __restrict__ t_ctx,
                                              const float* __restrict__ freq,
                                              const float* __restrict__ phase,
                                              unsigned short* __restrict__ xtb,
                                              unsigned short* __restrict__ xtTb,
                                              unsigned short* __restrict__ teb,
                                              unsigned short* __restrict__ teTb) {
    __shared__ unsigned short xs[Lc * 104];
    int b = blockIdx.x;
    int t = threadIdx.x;
    // phase 1: stage xs + write xtb
    for (int idx = t; idx < Lc * 12; idx += 256) {
        int l = idx / 12, c8 = idx - l * 12;
        unsigned short v[8];
        if (c8 < 8) {
            const float* s = x_ctx + ((size_t)(b * Lc + l)) * Dc + c8 * 8;
            float4 a = *(const float4*)s;
            float4 bq = *(const float4*)(s + 4);
            v[0]=f2bf(a.x); v[1]=f2bf(a.y); v[2]=f2bf(a.z); v[3]=f2bf(a.w);
            v[4]=f2bf(bq.x); v[5]=f2bf(bq.y); v[6]=f2bf(bq.z); v[7]=f2bf(bq.w);
        } else {
            int a = act_ctx[b * Lc + l];
            const float* s = emb + a * Ec + (c8 - 8) * 8;
            float4 e0 = *(const float4*)s;
            float4 e1 = *(const float4*)(s + 4);
            v[0]=f2bf(e0.x); v[1]=f2bf(e0.y); v[2]=f2bf(e0.z); v[3]=f2bf(e0.w);
            v[4]=f2bf(e1.x); v[5]=f2bf(e1.y); v[6]=f2bf(e1.z); v[7]=f2bf(e1.w);
        }
        uint4 u = *(const uint4*)v;
        *(uint4*)&xs[l * 104 + c8 * 8] = u;
        *(uint4*)&xtb[((size_t)(b * Lc + l)) * 96 + c8 * 8] = u;
    }
    __syncthreads();
    // phase 2: xtTb (transpose): 96 j x 28 chunks-of-8
    for (int idx = t; idx < 96 * 28; idx += 256) {
        int j = idx / 28, ch = idx - j * 28;
        int l0 = ch * 8;
        unsigned short v[8];
        #pragma unroll
        for (int k = 0; k < 8; ++k) {
            int l = l0 + k;
            v[k] = (l < Lc) ? xs[l * 104 + j] : (unsigned short)0;
        }
        *(uint4*)&xtTb[((size_t)(b * 96 + j)) * 224 + l0] = *(const uint4*)v;
    }
    // phase 3a: teb — 3*200 tasks
    for (int idx = t; idx < NLc * Lc; idx += 256) {
        int i = idx / Lc, l = idx - i * Lc;
        float lt = log1pf(fmaxf(t_ctx[b * Lc + l], 0.f));
        unsigned short v[16];
        #pragma unroll
        for (int j = 0; j < 8; ++j) {
            float z = lt * freq[i * Tc + j] + phase[i * Tc + j];
            v[j]     = f2bf(__sinf(z));
            v[8 + j] = f2bf(__cosf(z));
        }
        size_t base = ((size_t)i * TEBS + b * Lc + l) * 16;
        *(uint4*)&teb[base]     = *(const uint4*)v;
        *(uint4*)&teb[base + 8] = *(const uint4*)&v[8];
    }
    // phase 3b: teTb — 3*16*7 tasks, 32 l each
    for (int idx = t; idx < NLc * 16 * 7; idx += 256) {
        int i = idx / 112;
        int r = idx - i * 112;
        int f = r / 7, ch = r - f * 7;
        int l0 = ch * 32;
        float fr = freq[i * Tc + (f & 7)], ph = phase[i * Tc + (f & 7)];
        bool iscos = f >= 8;
        for (int k0 = 0; k0 < 32; k0 += 8) {
            unsigned short v[8];
            #pragma unroll
            for (int k = 0; k < 8; ++k) {
                int l = l0 + k0 + k;
                float val = 0.f;
                if (l < Lc) {
                    float lt = log1pf(fmaxf(t_ctx[b * Lc + l], 0.f));
                    float z = lt * fr + ph;
                    val = iscos ? __cosf(z) : __sinf(z);
                }
                v[k] = f2bf(val);
            }
            *(uint4*)&teTb[((size_t)i * Bc * 16 + b * 16 + f) * 224 + l0 + k0] = *(const uint4*)v;
        }
    }
}

// ---------------- qk2 = h @ Wbig[i]   (1024x256 @ 256x452)
__global__ __launch_bounds__(256) void k_qk2(const float* __restrict__ h,
                                             const float* __restrict__ wbig_l,
                                             float* __restrict__ qk2) {
    constexpr int R = 4;
    int rb = blockIdx.x & 255;
    int cb = blockIdx.x >> 8;       // 0..1
    int b0 = rb * R;
    int t = threadIdx.x;
    int c = cb * 256 + t;
    __shared__ float hl[R * Hc];
    for (int idx = t; idx < R * Hc; idx += 256) hl[idx] = h[b0 * Hc + idx];
    __syncthreads();
    if (c >= Q4) return;
    float acc[R];
    #pragma unroll
    for (int r = 0; r < R; ++r) acc[r] = 0.f;
    for (int e = 0; e < Hc; ++e) {
        float w = wbig_l[(size_t)e * Q4 + c];
        #pragma unroll
        for (int r = 0; r < R; ++r) acc[r] += hl[r * Hc + e] * w;
    }
    #pragma unroll
    for (int r = 0; r < R; ++r) qk2[(size_t)(b0 + r) * Q4 + c] = acc[r];
}

// ---------------- fused attention, all-MFMA. One block per b, 4 waves, ~13 KB LDS.
__global__ __launch_bounds__(256) void k_att(const int* __restrict__ act_ctx,
                                             const float* __restrict__ qk2,
                                             const unsigned short* __restrict__ xtb,
                                             const unsigned short* __restrict__ xtTb,
                                             const unsigned short* __restrict__ teb_l,
                                             const unsigned short* __restrict__ teTb_l,
                                             float* __restrict__ cagg) {
    __shared__ float qks[Q4];
    __shared__ float S[4][208];
    __shared__ unsigned short Pl[16][232];
    int b = blockIdx.x;
    int t = threadIdx.x;
    int wv = t >> 6, lane = t & 63;
    int kg = lane >> 4;

    for (int idx = t; idx < Q4; idx += 256) qks[idx] = qk2[(size_t)b * Q4 + idx];
    __syncthreads();

    // ---- B-fragments (query) in VGPRs
    bf16x8 bfr[4];
    {
        int h  = lane & 15;
        int kb = kg * 8;
        #pragma unroll
        for (int kk = 0; kk < 4; ++kk) {
            unsigned short tmp[8];
            #pragma unroll
            for (int j = 0; j < 8; ++j) {
                int k = kk * 32 + kb + j;
                float val = (h < 4 && k < QS) ? qks[h * QS + k] : 0.f;
                tmp[j] = f2bf(val);
            }
            bfr[kk] = *(const bf16x8*)tmp;
        }
    }

    // ---- QK: A-frags straight from global xtb/teb
    const unsigned short* xrow  = xtb   + (size_t)b * Lc * 96;
    const unsigned short* terow = teb_l + (size_t)b * Lc * 16;
    for (int tile = wv; tile < 13; tile += 4) {
        int r = tile * 16 + (lane & 15);
        bf16x8 a0 = *(const bf16x8*)(xrow + (size_t)r * 96 + kg * 8);
        bf16x8 a1 = *(const bf16x8*)(xrow + (size_t)r * 96 + 32 + kg * 8);
        bf16x8 a2 = *(const bf16x8*)(xrow + (size_t)r * 96 + 64 + kg * 8);
        bf16x8 a3;
        if (kg < 2) {
            a3 = *(const bf16x8*)(terow + (size_t)r * 16 + kg * 8);
        } else if (kg == 2) {
            unsigned short tmp[8] = {0x3F80u, 0, 0, 0, 0, 0, 0, 0};
            a3 = *(const bf16x8*)tmp;
        } else {
            bf16x8 z = {0, 0, 0, 0, 0, 0, 0, 0};
            a3 = z;
        }
        f32x4 acc = {0.f, 0.f, 0.f, 0.f};
        acc = __builtin_amdgcn_mfma_f32_16x16x32_bf16(a0, bfr[0], acc, 0, 0, 0);
        acc = __builtin_amdgcn_mfma_f32_16x16x32_bf16(a1, bfr[1], acc, 0, 0, 0);
        acc = __builtin_amdgcn_mfma_f32_16x16x32_bf16(a2, bfr[2], acc, 0, 0, 0);
        acc = __builtin_amdgcn_mfma_f32_16x16x32_bf16(a3, bfr[3], acc, 0, 0, 0);
        int h = lane & 15;
        if (h < 4) {
            int rb = tile * 16 + kg * 4;
            #pragma unroll
            for (int q = 0; q < 4; ++q) S[h][rb + q] = acc[q];
        }
    }
    // zero P (before barrier; softmax writes real values after)
    for (int idx = t; idx < 16 * 29; idx += 256) {
        int row = idx / 29, c8 = idx - row * 29;
        uint4 z = {0, 0, 0, 0};
        *(uint4*)&Pl[row][c8 * 8] = z;
    }
    __syncthreads();

    // ---- softmax (wave = head), write normalized P as bf16
    {
        int h = wv;
        float lv[4];
        #pragma unroll
        for (int k = 0; k < 4; ++k) {
            int l = lane + 64 * k;
            if (l < Lc) lv[k] = (act_ctx[b * Lc + l] > 0) ? S[h][l] : NEG_BIG;
            else        lv[k] = -INFINITY;
        }
        float m = fmaxf(fmaxf(lv[0], lv[1]), fmaxf(lv[2], lv[3]));
        #pragma unroll
        for (int off = 32; off >= 1; off >>= 1) m = fmaxf(m, __shfl_xor(m, off));
        float p[4];
        float ssum = 0.f;
        #pragma unroll
        for (int k = 0; k < 4; ++k) {
            int l = lane + 64 * k;
            p[k] = (l < Lc) ? __expf(lv[k] - m) : 0.f;
            ssum += p[k];
        }
        #pragma unroll
        for (int off = 32; off >= 1; off >>= 1) ssum += __shfl_xor(ssum, off);
        float sinv = 1.f / ssum;
        #pragma unroll
        for (int k = 0; k < 4; ++k) {
            int l = lane + 64 * k;
            if (l < Lc) Pl[h][l] = f2bf(p[k] * sinv);
        }
    }
    __syncthreads();

    // ---- PV via MFMA: out[h][j] = sum_l P[h][l]*xt[l][j]; B-frags from global xtT
    const unsigned short* xT  = xtTb   + (size_t)b * 96 * 224;
    const unsigned short* teT = teTb_l + (size_t)b * 16 * 224;
    for (int tile = wv; tile < 7; tile += 4) {
        int n = lane & 15;
        const unsigned short* brow = (tile < 6) ? (xT + ((size_t)(tile * 16 + n)) * 224)
                                                : (teT + (size_t)n * 224);
        f32x4 acc = {0.f, 0.f, 0.f, 0.f};
        #pragma unroll
        for (int kk = 0; kk < 7; ++kk) {
            bf16x8 a  = *(const bf16x8*)&Pl[lane & 15][kk * 32 + kg * 8];
            bf16x8 bb = *(const bf16x8*)(brow + kk * 32 + kg * 8);
            acc = __builtin_amdgcn_mfma_f32_16x16x32_bf16(a, bb, acc, 0, 0, 0);
        }
        if (kg == 0) {
            #pragma unroll
            for (int q = 0; q < 4; ++q)
                cagg[(size_t)b * CGW + q * CG + tile * 16 + n] = acc[q];
        }
    }
}

// ---------------- post-attention: aggproj(112) + h@Wres + LN1 + FF + LN2 -> h
__global__ __launch_bounds__(256) void k_post(const float* __restrict__ cagg,
                                              float* __restrict__ h,
                                              const float* __restrict__ wvp2,
                                              const float* __restrict__ Wres,
                                              const float* __restrict__ bres,
                                              const float* __restrict__ Wff1,
                                              const float* __restrict__ bff1,
                                              const float* __restrict__ Wff2,
                                              const float* __restrict__ bff2,
                                              const float* __restrict__ g1,
                                              const float* __restrict__ beta1,
                                              const float* __restrict__ g2,
                                              const float* __restrict__ beta2,
                                              int layer) {
    constexpr int R = 4;
    int b0 = blockIdx.x * R;
    int t = threadIdx.x;
    int wave = t >> 6, lane = t & 63;
    __shared__ float hl[R * Hc];
    __shared__ float cg[R * CGW];
    __shared__ float z1[R * Hc];
    __shared__ float ffa[R * Hc];
    __shared__ float red[R][2];
    for (int idx = t; idx < R * Hc; idx += 256) hl[idx] = h[b0 * Hc + idx];
    for (int idx = t; idx < R * CGW; idx += 256) cg[idx] = cagg[(size_t)b0 * CGW + idx];
    __syncthreads();

    const float* wvpL  = wvp2 + (size_t)layer * QS * Hc;
    const float* WresL = Wres + (size_t)layer * Hc * Hc;
    int hh = t >> 6;
    float acc[R];
    float bb = bres[layer * Hc + t] + wvpL[112 * Hc + t];
    #pragma unroll
    for (int r = 0; r < R; ++r) acc[r] = bb;
    for (int j = 0; j < CG; ++j) {
        float w = wvpL[j * Hc + t];
        #pragma unroll
        for (int r = 0; r < R; ++r) acc[r] += cg[r * CGW + hh * CG + j] * w;
    }
    for (int d = 0; d < Hc; ++d) {
        float w = WresL[d * Hc + t];
        #pragma unroll
        for (int r = 0; r < R; ++r) acc[r] += hl[r * Hc + d] * w;
    }
    // ---- LN1
    #pragma unroll
    for (int r = 0; r < R; ++r) z1[r * Hc + t] = acc[r];
    __syncthreads();
    {
        int r = wave;
        float v0 = z1[r * Hc + lane], v1 = z1[r * Hc + lane + 64];
        float v2 = z1[r * Hc + lane + 128], v3 = z1[r * Hc + lane + 192];
        float sm = v0 + v1 + v2 + v3;
        float sq = v0 * v0 + v1 * v1 + v2 * v2 + v3 * v3;
        #pragma unroll
        for (int off = 32; off >= 1; off >>= 1) { sm += __shfl_xor(sm, off); sq += __shfl_xor(sq, off); }
        if (lane == 0) {
            float mu = sm * (1.f / Hc);
            float var = sq * (1.f / Hc) - mu * mu;
            red[r][0] = mu;
            red[r][1] = rsqrtf(var + LN_EPS_V);
        }
    }
    __syncthreads();
    float z1v[R];
    float g1t = g1[layer * Hc + t], b1t = beta1[layer * Hc + t];
    #pragma unroll
    for (int r = 0; r < R; ++r) {
        z1v[r] = (acc[r] - red[r][0]) * red[r][1] * g1t + b1t;
        z1[r * Hc + t] = z1v[r];
    }
    __syncthreads();
    // ---- FF1
    const float* W1 = Wff1 + (size_t)layer * Hc * Hc;
    float f1[R];
    float bf1 = bff1[layer * Hc + t];
    #pragma unroll
    for (int r = 0; r < R; ++r) f1[r] = bf1;
    for (int d = 0; d < Hc; ++d) {
        float w = W1[d * Hc + t];
        #pragma unroll
        for (int r = 0; r < R; ++r) f1[r] += z1[r * Hc + d] * w;
    }
    #pragma unroll
    for (int r = 0; r < R; ++r) ffa[r * Hc + t] = fmaxf(f1[r], 0.f);
    __syncthreads();
    // ---- FF2 + residual
    const float* W2 = Wff2 + (size_t)layer * Hc * Hc;
    float y[R];
    float bf2 = bff2[layer * Hc + t];
    #pragma unroll
    for (int r = 0; r < R; ++r) y[r] = z1v[r] + bf2;
    for (int d = 0; d < Hc; ++d) {
        float w = W2[d * Hc + t];
        #pragma unroll
        for (int r = 0; r < R; ++r) y[r] += ffa[r * Hc + d] * w;
    }
    // ---- LN2 -> h
    __syncthreads();
    #pragma unroll
    for (int r = 0; r < R; ++r) z1[r * Hc + t] = y[r];
    __syncthreads();
    {
        int r = wave;
        float v0 = z1[r * Hc + lane], v1 = z1[r * Hc + lane + 64];
        float v2 = z1[r * Hc + lane + 128], v3 = z1[r * Hc + lane + 192];
        float sm = v0 + v1 + v2 + v3;
        float sq = v0 * v0 + v1 * v1 + v2 * v2 + v3 * v3;
        #pragma unroll
        for (int off = 32; off >= 1; off >>= 1) { sm += __shfl_xor(sm, off); sq += __shfl_xor(sq, off); }
        if (lane == 0) {
            float mu = sm * (1.f / Hc);
            float var = sq * (1.f / Hc) - mu * mu;
            red[r][0] = mu;
            red[r][1] = rsqrtf(var + LN_EPS_V);
        }
    }
    __syncthreads();
    float g2t = g2[layer * Hc + t], b2t = beta2[layer * Hc + t];
    #pragma unroll
    for (int r = 0; r < R; ++r)
        h[(b0 + r) * Hc + t] = (y[r] - red[r][0]) * red[r][1] * g2t + b2t;
}

// ---------------- head
__global__ __launch_bounds__(256) void k_head(const float* __restrict__ h,
                                              const float* __restrict__ W_ro,
                                              const float* __restrict__ b_ro,
                                              const float* __restrict__ W_cls,
                                              const float* __restrict__ b_cls,
                                              const float* __restrict__ W_dt,
                                              const float* __restrict__ b_dt,
                                              const float* __restrict__ W_rem,
                                              const float* __restrict__ b_rem,
                                              float* __restrict__ out) {
    constexpr int R = 8;
    int b0 = blockIdx.x * R;
    int t = threadIdx.x;
    int wave = t >> 6, lane = t & 63;
    __shared__ float hl[R * Hc], zl[R * Hc];
    __shared__ float wcls[Hc * Cc];
    __shared__ float wdt[Hc], wrem[Hc];
    for (int idx = t; idx < R * Hc; idx += 256) hl[idx] = h[b0 * Hc + idx];
    for (int idx = t; idx < Hc * Cc; idx += 256) wcls[idx] = W_cls[idx];
    wdt[t] = W_dt[t];
    wrem[t] = W_rem[t];
    __syncthreads();
    float acc[R];
    float br = b_ro[t];
    #pragma unroll
    for (int r = 0; r < R; ++r) acc[r] = br;
    for (int d = 0; d < Hc; ++d) {
        float w = W_ro[d * Hc + t];
        #pragma unroll
        for (int r = 0; r < R; ++r) acc[r] += hl[r * Hc + d] * w;
    }
    #pragma unroll
    for (int r = 0; r < R; ++r) zl[r * Hc + t] = fmaxf(acc[r], 0.f);
    __syncthreads();
    {
        int rr = t >> 5;
        int c = t & 31;
        float a = b_cls[c];
        for (int d = 0; d < Hc; ++d) a += zl[rr * Hc + d] * wcls[d * Cc + c];
        out[(size_t)(b0 + rr) * Cc + c] = a;
    }
    for (int rr = wave * 2; rr < wave * 2 + 2; ++rr) {
        float sd = 0.f, sr = 0.f;
        #pragma unroll
        for (int k2 = 0; k2 < 4; ++k2) {
            float zv = zl[rr * Hc + lane + 64 * k2];
            sd += zv * wdt[lane + 64 * k2];
            sr += zv * wrem[lane + 64 * k2];
        }
        #pragma unroll
        for (int off = 32; off >= 1; off >>= 1) { sd += __shfl_xor(sd, off); sr += __shfl_xor(sr, off); }
        if (lane == 0) {
            out[(size_t)Bc * Cc + b0 + rr]      = 1.f / (1.f + __expf(-(sd + b_dt[0])));
            out[(size_t)Bc * Cc + Bc + b0 + rr] = 1.f / (1.f + __expf(-(sr + b_rem[0])));
        }
    }
}

extern "C" void kernel_launch(void* const* d_in, const int* in_sizes, int n_in,
                              void* d_out, int out_size, void* d_ws, size_t ws_size,
                              hipStream_t stream) {
    const float* x_u      = (const float*)d_in[0];
    const float* x_ctx    = (const float*)d_in[1];
    const float* t_ctx    = (const float*)d_in[2];
    const int*   act_u    = (const int*)d_in[3];
    const int*   act_ctx  = (const int*)d_in[4];
    const float* emb      = (const float*)d_in[5];
    const float* W_in_self = (const float*)d_in[6];
    const float* b_in_self = (const float*)d_in[7];
    const float* W_in_ctx  = (const float*)d_in[8];
    const float* b_in_ctx  = (const float*)d_in[9];
    const float* freq  = (const float*)d_in[10];
    const float* phase = (const float*)d_in[11];
    const float* Wq    = (const float*)d_in[12];
    const float* Wk    = (const float*)d_in[13];
    const float* Wv    = (const float*)d_in[14];
    const float* Wres  = (const float*)d_in[15];
    const float* bres  = (const float*)d_in[16];
    const float* Wff1  = (const float*)d_in[17];
    const float* bff1  = (const float*)d_in[18];
    const float* Wff2  = (const float*)d_in[19];
    const float* bff2  = (const float*)d_in[20];
    const float* g1    = (const float*)d_in[21];
    const float* beta1 = (const float*)d_in[22];
    const float* g2    = (const float*)d_in[23];
    const float* beta2 = (const float*)d_in[24];
    const float* W_ro  = (const float*)d_in[25];
    const float* b_ro  = (const float*)d_in[26];
    const float* W_cls = (const float*)d_in[27];
    const float* b_cls = (const float*)d_in[28];
    const float* W_dt  = (const float*)d_in[29];
    const float* b_dt  = (const float*)d_in[30];
    const float* W_rem = (const float*)d_in[31];
    const float* b_rem = (const float*)d_in[32];

    float* ws    = (float*)d_ws;
    float* hbuf  = ws;                                    // B*H
    float* wqk   = hbuf  + (size_t)Bc * Hc;               // NL*H*QKW
    float* wbig  = wqk   + (size_t)NLc * Hc * QKW;        // NL*H*Q4
    float* qk2   = wbig  + (size_t)NLc * Hc * Q4;         // B*Q4
    float* cagg2 = qk2   + (size_t)Bc * Q4;               // B*CGW
    float* wvp2  = cagg2 + (size_t)Bc * CGW;              // NL*QS*H
    unsigned short* xtb  = (unsigned short*)(wvp2 + (size_t)NLc * QS * Hc);
    unsigned short* xtTb = xtb  + (size_t)XROWS * 96;
    unsigned short* teb  = xtTb + (size_t)Bc * 96 * 224;
    unsigned short* teTb = teb  + (size_t)NLc * TEBS * 16;
    size_t need = ((size_t)Bc * Hc + (size_t)NLc * Hc * QKW + (size_t)NLc * Hc * Q4
                  + (size_t)Bc * Q4 + (size_t)Bc * CGW + (size_t)NLc * QS * Hc) * 4
                + ((size_t)XROWS * 96 + (size_t)Bc * 96 * 224
                  + (size_t)NLc * TEBS * 16 + (size_t)NLc * Bc * 16 * 224) * 2;
    if (ws_size < need) return;

    float* out = (float*)d_out;

    k_wqk<<<NLc * Hc, 256, 0, stream>>>(Wq, Wk, wqk);
    k_wbig<<<NLc * Hc, 256, 0, stream>>>(wqk, W_in_ctx, b_in_ctx, wbig);
    k_wvp<<<NLc * QS, 256, 0, stream>>>(W_in_ctx, b_in_ctx, Wv, wvp2);
    k_h0<<<Bc / 16, 256, 0, stream>>>(x_u, act_u, emb, W_in_self, b_in_self, hbuf);
    k_prep<<<Bc, 256, 0, stream>>>(x_ctx, act_ctx, emb, t_ctx, freq, phase,
                                   xtb, xtTb, teb, teTb);

    for (int i = 0; i < NLc; ++i) {
        k_qk2<<<512, 256, 0, stream>>>(hbuf, wbig + (size_t)i * Hc * Q4, qk2);
        k_att<<<Bc, 256, 0, stream>>>(act_ctx, qk2, xtb, xtTb,
                                      teb + (size_t)i * TEBS * 16,
                                      teTb + (size_t)i * Bc * 16 * 224, cagg2);
        k_post<<<Bc / 4, 256, 0, stream>>>(cagg2, hbuf, wvp2, Wres, bres,
                                           Wff1, bff1, Wff2, bff2,
                                           g1, beta1, g2, beta2, i);
    }
    k_head<<<Bc / 8, 256, 0, stream>>>(hbuf, W_ro, b_ro, W_cls, b_cls,
                                       W_dt, b_dt, W_rem, b_rem, out);
}

// Round 5
// 364.686 us; speedup vs baseline: 3.0752x; 1.1610x over previous
//
#include <hip/hip_runtime.h>
#include <math.h>

namespace {
constexpr int Bc   = 1024;
constexpr int Lc   = 200;
constexpr int Dc   = 64;
constexpr int Ec   = 32;
constexpr int Pc   = 96;    // D+E
constexpr int Hc   = 256;
constexpr int Tc   = 8;
constexpr int NLc  = 3;
constexpr int KINc = 272;   // H+2T
constexpr int DHc  = 64;
constexpr int Cc   = 32;
constexpr int QKW  = 1088;  // NH*KIN
constexpr int QS   = 113;   // per-head query slots: 96 xc + 16 te + 1 bias-const
constexpr int Q4   = 452;   // 4*QS
constexpr int CG   = 112;   // per-head agg cols: 96 xc-agg + 16 te-agg
constexpr int CGW  = 448;   // 4*CG
constexpr int XROWS = Bc * Lc + 8;   // xtb rows (pad for r<=207 overrun)
constexpr int TEBS  = Bc * Lc + 8;   // per-layer teb rows
constexpr float LN_EPS_V = 1e-5f;
constexpr float NEG_BIG  = -1e9f;

typedef __attribute__((ext_vector_type(8))) short bf16x8;
typedef __attribute__((ext_vector_type(4))) float f32x4;

__device__ __forceinline__ unsigned short f2bf(float f) {
    union { float f; unsigned int u; } v; v.f = f;
    unsigned int u = v.u;
    unsigned int r = (u + 0x7fffu + ((u >> 16) & 1u)) >> 16;
    return (unsigned short)r;
}
}

// ---------------- wqk[i][e][hh*272+j] = sum_d Wq[i,e,hh*64+d] * Wk[i,j,hh*64+d]
__global__ __launch_bounds__(256) void k_wqk(const float* __restrict__ Wq,
                                             const float* __restrict__ Wk,
                                             float* __restrict__ wqk) {
    int blk = blockIdx.x;           // NLc*Hc blocks
    int i = blk >> 8;
    int e = blk & 255;
    int t = threadIdx.x;
    __shared__ float qrow[Hc];
    qrow[t] = Wq[i * Hc * Hc + e * Hc + t];
    __syncthreads();
    const float* wkL = Wk + (size_t)i * KINc * Hc;
    for (int c = t; c < QKW; c += 256) {
        int hh = c / KINc;
        int j  = c - hh * KINc;
        const float* wkr = wkL + j * Hc + hh * DHc;
        const float* qr  = qrow + hh * DHc;
        float acc = 0.f;
        #pragma unroll
        for (int d = 0; d < DHc; ++d) acc += qr[d] * wkr[d];
        wqk[(size_t)i * Hc * QKW + e * QKW + c] = acc;
    }
}

// ---------------- Wbig[i][e][h*113 + r]
__global__ __launch_bounds__(256) void k_wbig(const float* __restrict__ wqk,
                                              const float* __restrict__ W_in_ctx,
                                              const float* __restrict__ b_in_ctx,
                                              float* __restrict__ wbig) {
    int blk = blockIdx.x;           // NLc*Hc blocks
    int i = blk >> 8;
    int e = blk & 255;
    int t = threadIdx.x;
    __shared__ float wq[QKW];
    __shared__ float bl[Hc];
    for (int idx = t; idx < QKW; idx += 256) wq[idx] = wqk[(size_t)i * Hc * QKW + e * QKW + idx];
    bl[t] = b_in_ctx[t];
    __syncthreads();
    for (int slot = t; slot < Q4; slot += 256) {
        int h = slot / QS;
        int r = slot - h * QS;
        const float* wqh = wq + h * KINc;
        float acc = 0.f;
        if (r < 96) {
            const float* wr = W_in_ctx + r * Hc;
            for (int c = 0; c < Hc; ++c) acc += wqh[c] * wr[c];
        } else if (r < 112) {
            acc = wqh[256 + (r - 96)];
        } else {
            for (int c = 0; c < Hc; ++c) acc += wqh[c] * bl[c];
        }
        wbig[(size_t)(i * Hc + e) * Q4 + slot] = 0.125f * acc;
    }
}

// ---------------- wvp2[i][j][t]
__global__ __launch_bounds__(256) void k_wvp(const float* __restrict__ W_in_ctx,
                                             const float* __restrict__ b_in_ctx,
                                             const float* __restrict__ Wv,
                                             float* __restrict__ wvp2) {
    int blk = blockIdx.x;           // NLc*113 blocks
    int i = blk / QS;
    int j = blk - i * QS;
    int t = threadIdx.x;
    __shared__ float wrow[Hc];
    if (j < 96)       wrow[t] = W_in_ctx[j * Hc + t];
    else if (j == 112) wrow[t] = b_in_ctx[t];
    __syncthreads();
    const float* WvL = Wv + (size_t)i * KINc * Hc;
    float acc;
    if (j >= 96 && j < 112) {
        acc = WvL[(256 + (j - 96)) * Hc + t];
    } else {
        acc = 0.f;
        for (int c = 0; c < Hc; ++c) acc += wrow[c] * WvL[c * Hc + t];
    }
    wvp2[(size_t)blk * Hc + t] = acc;
}

// ---------------- h0 = [x_u, emb[act_u]] @ W_in_self + b
__global__ __launch_bounds__(256) void k_h0(const float* __restrict__ x_u,
                                            const int* __restrict__ act_u,
                                            const float* __restrict__ emb,
                                            const float* __restrict__ W,
                                            const float* __restrict__ bias,
                                            float* __restrict__ h) {
    constexpr int R = 16;
    int b0 = blockIdx.x * R;
    int t = threadIdx.x;
    __shared__ float xu[R * Pc];
    for (int idx = t; idx < R * Pc; idx += 256) {
        int r = idx / Pc, j = idx - r * Pc;
        int b = b0 + r;
        float v;
        if (j < Dc) v = x_u[b * Dc + j];
        else        v = emb[act_u[b] * Ec + (j - Dc)];
        xu[idx] = v;
    }
    __syncthreads();
    float acc[R];
    float bb = bias[t];
    #pragma unroll
    for (int r = 0; r < R; ++r) acc[r] = bb;
    for (int j = 0; j < Pc; ++j) {
        float w = W[j * Hc + t];
        #pragma unroll
        for (int r = 0; r < R; ++r) acc[r] += xu[r * Pc + j] * w;
    }
    #pragma unroll
    for (int r = 0; r < R; ++r) h[(b0 + r) * Hc + t] = acc[r];
}

// ---------------- prep (MFMA-transpose): xtb, xtTb, teb, teTb
// Transpose trick: D = mfma(A = xt 16x32 tile, B = shifted identity) gives
// D[m][n] = A[m][n+16*hh]; lane(n=lane&15, kg=lane>>4) holds 4 consecutive l
// (= kg*4+q) of column j -> conflict-free LDS writes, exact for bf16 values.
__global__ __launch_bounds__(256) void k_prep(const float* __restrict__ x_ctx,
                                              const int* __restrict__ act_ctx,
                                              const float* __restrict__ emb,
                                              const float* __restrict__ t_ctx,
                                              const float* __restrict__ freq,
                                              const float* __restrict__ phase,
                                              unsigned short* __restrict__ xtb,
                                              unsigned short* __restrict__ xtTb,
                                              unsigned short* __restrict__ teb,
                                              unsigned short* __restrict__ teTb) {
    constexpr int ST = 228;     // shorts; 456B row: 8B-aligned, 16-bank spread
    __shared__ __align__(16) unsigned short xsT[96 * ST];
    __shared__ float lt[Lc];
    int b = blockIdx.x;
    int t = threadIdx.x;
    int wv = t >> 6, lane = t & 63;
    int m = lane & 15, kg = lane >> 4;

    if (t < Lc) lt[t] = log1pf(fmaxf(t_ctx[b * Lc + t], 0.f));

    // shifted-identity B-fragments
    bf16x8 ifrag[2];
    #pragma unroll
    for (int hh = 0; hh < 2; ++hh) {
        unsigned short v[8];
        #pragma unroll
        for (int j8 = 0; j8 < 8; ++j8)
            v[j8] = (kg * 8 + j8 == m + 16 * hh) ? (unsigned short)0x3F80u : (unsigned short)0;
        ifrag[hh] = *(const bf16x8*)v;
    }

    for (int tile = wv; tile < 14; tile += 4) {
        int r = tile * 16 + m;              // local l
        bool valid = r < Lc;
        bf16x8 afr[3];
        // kk=0,1 from x_ctx
        #pragma unroll
        for (int kk = 0; kk < 2; ++kk) {
            unsigned short tmp[8];
            if (valid) {
                const float* s = x_ctx + ((size_t)(b * Lc + r)) * Dc + kk * 32 + kg * 8;
                float4 a0 = *(const float4*)s;
                float4 a1 = *(const float4*)(s + 4);
                tmp[0]=f2bf(a0.x); tmp[1]=f2bf(a0.y); tmp[2]=f2bf(a0.z); tmp[3]=f2bf(a0.w);
                tmp[4]=f2bf(a1.x); tmp[5]=f2bf(a1.y); tmp[6]=f2bf(a1.z); tmp[7]=f2bf(a1.w);
            } else {
                #pragma unroll
                for (int j = 0; j < 8; ++j) tmp[j] = 0;
            }
            afr[kk] = *(const bf16x8*)tmp;
        }
        // kk=2 from emb
        {
            unsigned short tmp[8];
            if (valid) {
                int a = act_ctx[b * Lc + r];
                const float* s = emb + (size_t)a * Ec + kg * 8;
                float4 e0 = *(const float4*)s;
                float4 e1 = *(const float4*)(s + 4);
                tmp[0]=f2bf(e0.x); tmp[1]=f2bf(e0.y); tmp[2]=f2bf(e0.z); tmp[3]=f2bf(e0.w);
                tmp[4]=f2bf(e1.x); tmp[5]=f2bf(e1.y); tmp[6]=f2bf(e1.z); tmp[7]=f2bf(e1.w);
            } else {
                #pragma unroll
                for (int j = 0; j < 8; ++j) tmp[j] = 0;
            }
            afr[2] = *(const bf16x8*)tmp;
        }
        // row-major global write (per-instruction fully coalesced across lanes)
        if (valid) {
            unsigned short* dst = xtb + ((size_t)(b * Lc + r)) * 96;
            *(uint4*)(dst + kg * 8)      = *(const uint4*)&afr[0];
            *(uint4*)(dst + 32 + kg * 8) = *(const uint4*)&afr[1];
            *(uint4*)(dst + 64 + kg * 8) = *(const uint4*)&afr[2];
        }
        // transpose via MFMA, write columns to LDS
        #pragma unroll
        for (int kk = 0; kk < 3; ++kk) {
            #pragma unroll
            for (int hh = 0; hh < 2; ++hh) {
                f32x4 d = {0.f, 0.f, 0.f, 0.f};
                d = __builtin_amdgcn_mfma_f32_16x16x32_bf16(afr[kk], ifrag[hh], d, 0, 0, 0);
                int j  = kk * 32 + hh * 16 + m;
                int l0 = tile * 16 + kg * 4;
                unsigned int u0 = (unsigned int)f2bf(d[0]) | ((unsigned int)f2bf(d[1]) << 16);
                unsigned int u1 = (unsigned int)f2bf(d[2]) | ((unsigned int)f2bf(d[3]) << 16);
                uint2 uu; uu.x = u0; uu.y = u1;
                *(uint2*)&xsT[j * ST + l0] = uu;
            }
        }
    }
    __syncthreads();

    // copy-out xtTb rows (coalesced)
    for (int idx = t; idx < 96 * 28; idx += 256) {
        int j = idx / 28, ch = idx - j * 28;
        uint2 a  = *(const uint2*)&xsT[j * ST + ch * 8];
        uint2 b2 = *(const uint2*)&xsT[j * ST + ch * 8 + 4];
        uint4 o; o.x = a.x; o.y = a.y; o.z = b2.x; o.w = b2.y;
        *(uint4*)&xtTb[((size_t)(b * 96 + j)) * 224 + ch * 8] = o;
    }
    // teb[i][b*L+l][16]
    for (int idx = t; idx < NLc * Lc; idx += 256) {
        int i = idx / Lc, l = idx - i * Lc;
        float L = lt[l];
        unsigned short v[16];
        #pragma unroll
        for (int j = 0; j < 8; ++j) {
            float z = L * freq[i * Tc + j] + phase[i * Tc + j];
            v[j]     = f2bf(__sinf(z));
            v[8 + j] = f2bf(__cosf(z));
        }
        size_t base = ((size_t)i * TEBS + b * Lc + l) * 16;
        *(uint4*)&teb[base]     = *(const uint4*)v;
        *(uint4*)&teb[base + 8] = *(const uint4*)&v[8];
    }
    // teTb[i][b][f][224]
    for (int idx = t; idx < NLc * 16 * 28; idx += 256) {
        int i  = idx / 448;
        int r2 = idx - i * 448;
        int f  = r2 / 28, ch = r2 - f * 28;
        int l0 = ch * 8;
        float fr = freq[i * Tc + (f & 7)], ph = phase[i * Tc + (f & 7)];
        bool iscos = f >= 8;
        unsigned short v[8];
        #pragma unroll
        for (int k = 0; k < 8; ++k) {
            int l = l0 + k;
            float val = 0.f;
            if (l < Lc) {
                float z = lt[l] * fr + ph;
                val = iscos ? __cosf(z) : __sinf(z);
            }
            v[k] = f2bf(val);
        }
        *(uint4*)&teTb[((size_t)i * Bc * 16 + b * 16 + f) * 224 + l0] = *(const uint4*)v;
    }
}

// ---------------- qk2 = h @ Wbig[i]   (1024x256 @ 256x452)
__global__ __launch_bounds__(256) void k_qk2(const float* __restrict__ h,
                                             const float* __restrict__ wbig_l,
                                             float* __restrict__ qk2) {
    constexpr int R = 4;
    int rb = blockIdx.x & 255;
    int cb = blockIdx.x >> 8;       // 0..1
    int b0 = rb * R;
    int t = threadIdx.x;
    int c = cb * 256 + t;
    __shared__ float hl[R * Hc];
    for (int idx = t; idx < R * Hc; idx += 256) hl[idx] = h[b0 * Hc + idx];
    __syncthreads();
    if (c >= Q4) return;
    float acc[R];
    #pragma unroll
    for (int r = 0; r < R; ++r) acc[r] = 0.f;
    for (int e = 0; e < Hc; ++e) {
        float w = wbig_l[(size_t)e * Q4 + c];
        #pragma unroll
        for (int r = 0; r < R; ++r) acc[r] += hl[r * Hc + e] * w;
    }
    #pragma unroll
    for (int r = 0; r < R; ++r) qk2[(size_t)(b0 + r) * Q4 + c] = acc[r];
}

// ---------------- fused attention, all-MFMA. One block per b, 4 waves.
__global__ __launch_bounds__(256) void k_att(const int* __restrict__ act_ctx,
                                             const float* __restrict__ qk2,
                                             const unsigned short* __restrict__ xtb,
                                             const unsigned short* __restrict__ xtTb,
                                             const unsigned short* __restrict__ teb_l,
                                             const unsigned short* __restrict__ teTb_l,
                                             float* __restrict__ cagg) {
    __shared__ float qks[Q4];
    __shared__ float S[4][208];
    __shared__ unsigned short Pl[16][232];
    int b = blockIdx.x;
    int t = threadIdx.x;
    int wv = t >> 6, lane = t & 63;
    int kg = lane >> 4;

    for (int idx = t; idx < Q4; idx += 256) qks[idx] = qk2[(size_t)b * Q4 + idx];
    __syncthreads();

    // ---- B-fragments (query) in VGPRs
    bf16x8 bfr[4];
    {
        int h  = lane & 15;
        int kb = kg * 8;
        #pragma unroll
        for (int kk = 0; kk < 4; ++kk) {
            unsigned short tmp[8];
            #pragma unroll
            for (int j = 0; j < 8; ++j) {
                int k = kk * 32 + kb + j;
                float val = (h < 4 && k < QS) ? qks[h * QS + k] : 0.f;
                tmp[j] = f2bf(val);
            }
            bfr[kk] = *(const bf16x8*)tmp;
        }
    }

    // ---- QK: A-frags straight from global xtb/teb
    const unsigned short* xrow  = xtb   + (size_t)b * Lc * 96;
    const unsigned short* terow = teb_l + (size_t)b * Lc * 16;
    for (int tile = wv; tile < 13; tile += 4) {
        int r = tile * 16 + (lane & 15);
        bf16x8 a0 = *(const bf16x8*)(xrow + (size_t)r * 96 + kg * 8);
        bf16x8 a1 = *(const bf16x8*)(xrow + (size_t)r * 96 + 32 + kg * 8);
        bf16x8 a2 = *(const bf16x8*)(xrow + (size_t)r * 96 + 64 + kg * 8);
        bf16x8 a3;
        if (kg < 2) {
            a3 = *(const bf16x8*)(terow + (size_t)r * 16 + kg * 8);
        } else if (kg == 2) {
            unsigned short tmp[8] = {0x3F80u, 0, 0, 0, 0, 0, 0, 0};
            a3 = *(const bf16x8*)tmp;
        } else {
            bf16x8 z = {0, 0, 0, 0, 0, 0, 0, 0};
            a3 = z;
        }
        f32x4 acc = {0.f, 0.f, 0.f, 0.f};
        acc = __builtin_amdgcn_mfma_f32_16x16x32_bf16(a0, bfr[0], acc, 0, 0, 0);
        acc = __builtin_amdgcn_mfma_f32_16x16x32_bf16(a1, bfr[1], acc, 0, 0, 0);
        acc = __builtin_amdgcn_mfma_f32_16x16x32_bf16(a2, bfr[2], acc, 0, 0, 0);
        acc = __builtin_amdgcn_mfma_f32_16x16x32_bf16(a3, bfr[3], acc, 0, 0, 0);
        int h = lane & 15;
        if (h < 4) {
            int rb = tile * 16 + kg * 4;
            #pragma unroll
            for (int q = 0; q < 4; ++q) S[h][rb + q] = acc[q];
        }
    }
    // zero P (before barrier; softmax writes real values after)
    for (int idx = t; idx < 16 * 29; idx += 256) {
        int row = idx / 29, c8 = idx - row * 29;
        uint4 z = {0, 0, 0, 0};
        *(uint4*)&Pl[row][c8 * 8] = z;
    }
    __syncthreads();

    // ---- softmax (wave = head), write normalized P as bf16
    {
        int h = wv;
        float lv[4];
        #pragma unroll
        for (int k = 0; k < 4; ++k) {
            int l = lane + 64 * k;
            if (l < Lc) lv[k] = (act_ctx[b * Lc + l] > 0) ? S[h][l] : NEG_BIG;
            else        lv[k] = -INFINITY;
        }
        float m = fmaxf(fmaxf(lv[0], lv[1]), fmaxf(lv[2], lv[3]));
        #pragma unroll
        for (int off = 32; off >= 1; off >>= 1) m = fmaxf(m, __shfl_xor(m, off));
        float p[4];
        float ssum = 0.f;
        #pragma unroll
        for (int k = 0; k < 4; ++k) {
            int l = lane + 64 * k;
            p[k] = (l < Lc) ? __expf(lv[k] - m) : 0.f;
            ssum += p[k];
        }
        #pragma unroll
        for (int off = 32; off >= 1; off >>= 1) ssum += __shfl_xor(ssum, off);
        float sinv = 1.f / ssum;
        #pragma unroll
        for (int k = 0; k < 4; ++k) {
            int l = lane + 64 * k;
            if (l < Lc) Pl[h][l] = f2bf(p[k] * sinv);
        }
    }
    __syncthreads();

    // ---- PV via MFMA
    const unsigned short* xT  = xtTb   + (size_t)b * 96 * 224;
    const unsigned short* teT = teTb_l + (size_t)b * 16 * 224;
    for (int tile = wv; tile < 7; tile += 4) {
        int n = lane & 15;
        const unsigned short* brow = (tile < 6) ? (xT + ((size_t)(tile * 16 + n)) * 224)
                                                : (teT + (size_t)n * 224);
        f32x4 acc = {0.f, 0.f, 0.f, 0.f};
        #pragma unroll
        for (int kk = 0; kk < 7; ++kk) {
            bf16x8 a  = *(const bf16x8*)&Pl[lane & 15][kk * 32 + kg * 8];
            bf16x8 bb = *(const bf16x8*)(brow + kk * 32 + kg * 8);
            acc = __builtin_amdgcn_mfma_f32_16x16x32_bf16(a, bb, acc, 0, 0, 0);
        }
        if (kg == 0) {
            #pragma unroll
            for (int q = 0; q < 4; ++q)
                cagg[(size_t)b * CGW + q * CG + tile * 16 + n] = acc[q];
        }
    }
}

// ---------------- post-attention: aggproj(112) + h@Wres + LN1 + FF + LN2 -> h
__global__ __launch_bounds__(256) void k_post(const float* __restrict__ cagg,
                                              float* __restrict__ h,
                                              const float* __restrict__ wvp2,
                                              const float* __restrict__ Wres,
                                              const float* __restrict__ bres,
                                              const float* __restrict__ Wff1,
                                              const float* __restrict__ bff1,
                                              const float* __restrict__ Wff2,
                                              const float* __restrict__ bff2,
                                              const float* __restrict__ g1,
                                              const float* __restrict__ beta1,
                                              const float* __restrict__ g2,
                                              const float* __restrict__ beta2,
                                              int layer) {
    constexpr int R = 4;
    int b0 = blockIdx.x * R;
    int t = threadIdx.x;
    int wave = t >> 6, lane = t & 63;
    __shared__ float hl[R * Hc];
    __shared__ float cg[R * CGW];
    __shared__ float z1[R * Hc];
    __shared__ float ffa[R * Hc];
    __shared__ float red[R][2];
    for (int idx = t; idx < R * Hc; idx += 256) hl[idx] = h[b0 * Hc + idx];
    for (int idx = t; idx < R * CGW; idx += 256) cg[idx] = cagg[(size_t)b0 * CGW + idx];
    __syncthreads();

    const float* wvpL  = wvp2 + (size_t)layer * QS * Hc;
    const float* WresL = Wres + (size_t)layer * Hc * Hc;
    int hh = t >> 6;
    float acc[R];
    float bb = bres[layer * Hc + t] + wvpL[112 * Hc + t];
    #pragma unroll
    for (int r = 0; r < R; ++r) acc[r] = bb;
    for (int j = 0; j < CG; ++j) {
        float w = wvpL[j * Hc + t];
        #pragma unroll
        for (int r = 0; r < R; ++r) acc[r] += cg[r * CGW + hh * CG + j] * w;
    }
    for (int d = 0; d < Hc; ++d) {
        float w = WresL[d * Hc + t];
        #pragma unroll
        for (int r = 0; r < R; ++r) acc[r] += hl[r * Hc + d] * w;
    }
    // ---- LN1
    #pragma unroll
    for (int r = 0; r < R; ++r) z1[r * Hc + t] = acc[r];
    __syncthreads();
    {
        int r = wave;
        float v0 = z1[r * Hc + lane], v1 = z1[r * Hc + lane + 64];
        float v2 = z1[r * Hc + lane + 128], v3 = z1[r * Hc + lane + 192];
        float sm = v0 + v1 + v2 + v3;
        float sq = v0 * v0 + v1 * v1 + v2 * v2 + v3 * v3;
        #pragma unroll
        for (int off = 32; off >= 1; off >>= 1) { sm += __shfl_xor(sm, off); sq += __shfl_xor(sq, off); }
        if (lane == 0) {
            float mu = sm * (1.f / Hc);
            float var = sq * (1.f / Hc) - mu * mu;
            red[r][0] = mu;
            red[r][1] = rsqrtf(var + LN_EPS_V);
        }
    }
    __syncthreads();
    float z1v[R];
    float g1t = g1[layer * Hc + t], b1t = beta1[layer * Hc + t];
    #pragma unroll
    for (int r = 0; r < R; ++r) {
        z1v[r] = (acc[r] - red[r][0]) * red[r][1] * g1t + b1t;
        z1[r * Hc + t] = z1v[r];
    }
    __syncthreads();
    // ---- FF1
    const float* W1 = Wff1 + (size_t)layer * Hc * Hc;
    float f1[R];
    float bf1 = bff1[layer * Hc + t];
    #pragma unroll
    for (int r = 0; r < R; ++r) f1[r] = bf1;
    for (int d = 0; d < Hc; ++d) {
        float w = W1[d * Hc + t];
        #pragma unroll
        for (int r = 0; r < R; ++r) f1[r] += z1[r * Hc + d] * w;
    }
    #pragma unroll
    for (int r = 0; r < R; ++r) ffa[r * Hc + t] = fmaxf(f1[r], 0.f);
    __syncthreads();
    // ---- FF2 + residual
    const float* W2 = Wff2 + (size_t)layer * Hc * Hc;
    float y[R];
    float bf2 = bff2[layer * Hc + t];
    #pragma unroll
    for (int r = 0; r < R; ++r) y[r] = z1v[r] + bf2;
    for (int d = 0; d < Hc; ++d) {
        float w = W2[d * Hc + t];
        #pragma unroll
        for (int r = 0; r < R; ++r) y[r] += ffa[r * Hc + d] * w;
    }
    // ---- LN2 -> h
    __syncthreads();
    #pragma unroll
    for (int r = 0; r < R; ++r) z1[r * Hc + t] = y[r];
    __syncthreads();
    {
        int r = wave;
        float v0 = z1[r * Hc + lane], v1 = z1[r * Hc + lane + 64];
        float v2 = z1[r * Hc + lane + 128], v3 = z1[r * Hc + lane + 192];
        float sm = v0 + v1 + v2 + v3;
        float sq = v0 * v0 + v1 * v1 + v2 * v2 + v3 * v3;
        #pragma unroll
        for (int off = 32; off >= 1; off >>= 1) { sm += __shfl_xor(sm, off); sq += __shfl_xor(sq, off); }
        if (lane == 0) {
            float mu = sm * (1.f / Hc);
            float var = sq * (1.f / Hc) - mu * mu;
            red[r][0] = mu;
            red[r][1] = rsqrtf(var + LN_EPS_V);
        }
    }
    __syncthreads();
    float g2t = g2[layer * Hc + t], b2t = beta2[layer * Hc + t];
    #pragma unroll
    for (int r = 0; r < R; ++r)
        h[(b0 + r) * Hc + t] = (y[r] - red[r][0]) * red[r][1] * g2t + b2t;
}

// ---------------- head
__global__ __launch_bounds__(256) void k_head(const float* __restrict__ h,
                                              const float* __restrict__ W_ro,
                                              const float* __restrict__ b_ro,
                                              const float* __restrict__ W_cls,
                                              const float* __restrict__ b_cls,
                                              const float* __restrict__ W_dt,
                                              const float* __restrict__ b_dt,
                                              const float* __restrict__ W_rem,
                                              const float* __restrict__ b_rem,
                                              float* __restrict__ out) {
    constexpr int R = 8;
    int b0 = blockIdx.x * R;
    int t = threadIdx.x;
    int wave = t >> 6, lane = t & 63;
    __shared__ float hl[R * Hc], zl[R * Hc];
    __shared__ float wcls[Hc * Cc];
    __shared__ float wdt[Hc], wrem[Hc];
    for (int idx = t; idx < R * Hc; idx += 256) hl[idx] = h[b0 * Hc + idx];
    for (int idx = t; idx < Hc * Cc; idx += 256) wcls[idx] = W_cls[idx];
    wdt[t] = W_dt[t];
    wrem[t] = W_rem[t];
    __syncthreads();
    float acc[R];
    float br = b_ro[t];
    #pragma unroll
    for (int r = 0; r < R; ++r) acc[r] = br;
    for (int d = 0; d < Hc; ++d) {
        float w = W_ro[d * Hc + t];
        #pragma unroll
        for (int r = 0; r < R; ++r) acc[r] += hl[r * Hc + d] * w;
    }
    #pragma unroll
    for (int r = 0; r < R; ++r) zl[r * Hc + t] = fmaxf(acc[r], 0.f);
    __syncthreads();
    {
        int rr = t >> 5;
        int c = t & 31;
        float a = b_cls[c];
        for (int d = 0; d < Hc; ++d) a += zl[rr * Hc + d] * wcls[d * Cc + c];
        out[(size_t)(b0 + rr) * Cc + c] = a;
    }
    for (int rr = wave * 2; rr < wave * 2 + 2; ++rr) {
        float sd = 0.f, sr = 0.f;
        #pragma unroll
        for (int k2 = 0; k2 < 4; ++k2) {
            float zv = zl[rr * Hc + lane + 64 * k2];
            sd += zv * wdt[lane + 64 * k2];
            sr += zv * wrem[lane + 64 * k2];
        }
        #pragma unroll
        for (int off = 32; off >= 1; off >>= 1) { sd += __shfl_xor(sd, off); sr += __shfl_xor(sr, off); }
        if (lane == 0) {
            out[(size_t)Bc * Cc + b0 + rr]      = 1.f / (1.f + __expf(-(sd + b_dt[0])));
            out[(size_t)Bc * Cc + Bc + b0 + rr] = 1.f / (1.f + __expf(-(sr + b_rem[0])));
        }
    }
}

extern "C" void kernel_launch(void* const* d_in, const int* in_sizes, int n_in,
                              void* d_out, int out_size, void* d_ws, size_t ws_size,
                              hipStream_t stream) {
    const float* x_u      = (const float*)d_in[0];
    const float* x_ctx    = (const float*)d_in[1];
    const float* t_ctx    = (const float*)d_in[2];
    const int*   act_u    = (const int*)d_in[3];
    const int*   act_ctx  = (const int*)d_in[4];
    const float* emb      = (const float*)d_in[5];
    const float* W_in_self = (const float*)d_in[6];
    const float* b_in_self = (const float*)d_in[7];
    const float* W_in_ctx  = (const float*)d_in[8];
    const float* b_in_ctx  = (const float*)d_in[9];
    const float* freq  = (const float*)d_in[10];
    const float* phase = (const float*)d_in[11];
    const float* Wq    = (const float*)d_in[12];
    const float* Wk    = (const float*)d_in[13];
    const float* Wv    = (const float*)d_in[14];
    const float* Wres  = (const float*)d_in[15];
    const float* bres  = (const float*)d_in[16];
    const float* Wff1  = (const float*)d_in[17];
    const float* bff1  = (const float*)d_in[18];
    const float* Wff2  = (const float*)d_in[19];
    const float* bff2  = (const float*)d_in[20];
    const float* g1    = (const float*)d_in[21];
    const float* beta1 = (const float*)d_in[22];
    const float* g2    = (const float*)d_in[23];
    const float* beta2 = (const float*)d_in[24];
    const float* W_ro  = (const float*)d_in[25];
    const float* b_ro  = (const float*)d_in[26];
    const float* W_cls = (const float*)d_in[27];
    const float* b_cls = (const float*)d_in[28];
    const float* W_dt  = (const float*)d_in[29];
    const float* b_dt  = (const float*)d_in[30];
    const float* W_rem = (const float*)d_in[31];
    const float* b_rem = (const float*)d_in[32];

    float* ws    = (float*)d_ws;
    float* hbuf  = ws;                                    // B*H
    float* wqk   = hbuf  + (size_t)Bc * Hc;               // NL*H*QKW
    float* wbig  = wqk   + (size_t)NLc * Hc * QKW;        // NL*H*Q4
    float* qk2   = wbig  + (size_t)NLc * Hc * Q4;         // B*Q4
    float* cagg2 = qk2   + (size_t)Bc * Q4;               // B*CGW
    float* wvp2  = cagg2 + (size_t)Bc * CGW;              // NL*QS*H
    unsigned short* xtb  = (unsigned short*)(wvp2 + (size_t)NLc * QS * Hc);
    unsigned short* xtTb = xtb  + (size_t)XROWS * 96;
    unsigned short* teb  = xtTb + (size_t)Bc * 96 * 224;
    unsigned short* teTb = teb  + (size_t)NLc * TEBS * 16;
    size_t need = ((size_t)Bc * Hc + (size_t)NLc * Hc * QKW + (size_t)NLc * Hc * Q4
                  + (size_t)Bc * Q4 + (size_t)Bc * CGW + (size_t)NLc * QS * Hc) * 4
                + ((size_t)XROWS * 96 + (size_t)Bc * 96 * 224
                  + (size_t)NLc * TEBS * 16 + (size_t)NLc * Bc * 16 * 224) * 2;
    if (ws_size < need) return;

    float* out = (float*)d_out;

    k_wqk<<<NLc * Hc, 256, 0, stream>>>(Wq, Wk, wqk);
    k_wbig<<<NLc * Hc, 256, 0, stream>>>(wqk, W_in_ctx, b_in_ctx, wbig);
    k_wvp<<<NLc * QS, 256, 0, stream>>>(W_in_ctx, b_in_ctx, Wv, wvp2);
    k_h0<<<Bc / 16, 256, 0, stream>>>(x_u, act_u, emb, W_in_self, b_in_self, hbuf);
    k_prep<<<Bc, 256, 0, stream>>>(x_ctx, act_ctx, emb, t_ctx, freq, phase,
                                   xtb, xtTb, teb, teTb);

    for (int i = 0; i < NLc; ++i) {
        k_qk2<<<512, 256, 0, stream>>>(hbuf, wbig + (size_t)i * Hc * Q4, qk2);
        k_att<<<Bc, 256, 0, stream>>>(act_ctx, qk2, xtb, xtTb,
                                      teb + (size_t)i * TEBS * 16,
                                      teTb + (size_t)i * Bc * 16 * 224, cagg2);
        k_post<<<Bc / 4, 256, 0, stream>>>(cagg2, hbuf, wvp2, Wres, bres,
                                           Wff1, bff1, Wff2, bff2,
                                           g1, beta1, g2, beta2, i);
    }
    k_head<<<Bc / 8, 256, 0, stream>>>(hbuf, W_ro, b_ro, W_cls, b_cls,
                                       W_dt, b_dt, W_rem, b_rem, out);
}

// Round 6
// 283.583 us; speedup vs baseline: 3.9547x; 1.2860x over previous
//
#include <hip/hip_runtime.h>
#include <math.h>

namespace {
constexpr int Bc   = 1024;
constexpr int Lc   = 200;
constexpr int Dc   = 64;
constexpr int Ec   = 32;
constexpr int Pc   = 96;    // D+E
constexpr int Hc   = 256;
constexpr int Tc   = 8;
constexpr int NLc  = 3;
constexpr int KINc = 272;   // H+2T
constexpr int DHc  = 64;
constexpr int Cc   = 32;
constexpr int QKW  = 1088;  // NH*KIN
constexpr int QS   = 113;   // per-head query slots: 96 xc + 16 te + 1 bias-const
constexpr int Q4   = 452;   // 4*QS
constexpr int QP   = 464;   // padded qk2 row (29 * 16)
constexpr int CG   = 112;   // per-head agg cols
constexpr int CGW  = 448;   // 4*CG
constexpr int XROWS = Bc * Lc + 8;
constexpr int TEBS  = Bc * Lc + 8;
constexpr float LN_EPS_V = 1e-5f;
constexpr float NEG_BIG  = -1e9f;

typedef __attribute__((ext_vector_type(8))) short bf16x8;
typedef __attribute__((ext_vector_type(4))) float f32x4;

__device__ __forceinline__ unsigned short f2bf(float f) {
    union { float f; unsigned int u; } v; v.f = f;
    unsigned int u = v.u;
    unsigned int r = (u + 0x7fffu + ((u >> 16) & 1u)) >> 16;
    return (unsigned short)r;
}
}

// ---------------- wqk[i][e][hh*272+j] = sum_d Wq[i,e,hh*64+d] * Wk[i,j,hh*64+d]
__global__ __launch_bounds__(256) void k_wqk(const float* __restrict__ Wq,
                                             const float* __restrict__ Wk,
                                             float* __restrict__ wqk) {
    int blk = blockIdx.x;
    int i = blk >> 8;
    int e = blk & 255;
    int t = threadIdx.x;
    __shared__ float qrow[Hc];
    qrow[t] = Wq[i * Hc * Hc + e * Hc + t];
    __syncthreads();
    const float* wkL = Wk + (size_t)i * KINc * Hc;
    for (int c = t; c < QKW; c += 256) {
        int hh = c / KINc;
        int j  = c - hh * KINc;
        const float* wkr = wkL + j * Hc + hh * DHc;
        const float* qr  = qrow + hh * DHc;
        float acc = 0.f;
        #pragma unroll
        for (int d = 0; d < DHc; ++d) acc += qr[d] * wkr[d];
        wqk[(size_t)i * Hc * QKW + e * QKW + c] = acc;
    }
}

// ---------------- Wbig[i][e][h*113 + r]  (fp32, scale folded)
__global__ __launch_bounds__(256) void k_wbig(const float* __restrict__ wqk,
                                              const float* __restrict__ W_in_ctx,
                                              const float* __restrict__ b_in_ctx,
                                              float* __restrict__ wbig) {
    int blk = blockIdx.x;
    int i = blk >> 8;
    int e = blk & 255;
    int t = threadIdx.x;
    __shared__ float wq[QKW];
    __shared__ float bl[Hc];
    for (int idx = t; idx < QKW; idx += 256) wq[idx] = wqk[(size_t)i * Hc * QKW + e * QKW + idx];
    bl[t] = b_in_ctx[t];
    __syncthreads();
    for (int slot = t; slot < Q4; slot += 256) {
        int h = slot / QS;
        int r = slot - h * QS;
        const float* wqh = wq + h * KINc;
        float acc = 0.f;
        if (r < 96) {
            const float* wr = W_in_ctx + r * Hc;
            for (int c = 0; c < Hc; ++c) acc += wqh[c] * wr[c];
        } else if (r < 112) {
            acc = wqh[256 + (r - 96)];
        } else {
            for (int c = 0; c < Hc; ++c) acc += wqh[c] * bl[c];
        }
        wbig[(size_t)(i * Hc + e) * Q4 + slot] = 0.125f * acc;
    }
}

// ---------------- wvp2[i][j][t]
__global__ __launch_bounds__(256) void k_wvp(const float* __restrict__ W_in_ctx,
                                             const float* __restrict__ b_in_ctx,
                                             const float* __restrict__ Wv,
                                             float* __restrict__ wvp2) {
    int blk = blockIdx.x;
    int i = blk / QS;
    int j = blk - i * QS;
    int t = threadIdx.x;
    __shared__ float wrow[Hc];
    if (j < 96)       wrow[t] = W_in_ctx[j * Hc + t];
    else if (j == 112) wrow[t] = b_in_ctx[t];
    __syncthreads();
    const float* WvL = Wv + (size_t)i * KINc * Hc;
    float acc;
    if (j >= 96 && j < 112) {
        acc = WvL[(256 + (j - 96)) * Hc + t];
    } else {
        acc = 0.f;
        for (int c = 0; c < Hc; ++c) acc += wrow[c] * WvL[c * Hc + t];
    }
    wvp2[(size_t)blk * Hc + t] = acc;
}

// ---------------- frag preps: bf16 MFMA B-fragment layout
// frag (kk, ct, lane): 8 bf16 = W[kk*32 + (lane>>4)*8 + j][ct*16 + (lane&15)]
// Wcat: K=704 (448 wvp zero-expanded + 256 Wres), N=256
__global__ __launch_bounds__(64) void k_fcat(const float* __restrict__ wvp2,
                                             const float* __restrict__ Wres,
                                             unsigned short* __restrict__ wcatF) {
    int blk = blockIdx.x;               // NLc*352
    int i = blk / 352;
    int r = blk - i * 352;
    int kk = r >> 4, ct = r & 15;
    int lane = threadIdx.x;
    int c = ct * 16 + (lane & 15);
    int kb = kk * 32 + (lane >> 4) * 8;
    unsigned short v[8];
    #pragma unroll
    for (int j = 0; j < 8; ++j) {
        int k = kb + j;
        float val;
        if (k < 448) {
            int hh = k / 112, jj = k - hh * 112;
            val = ((c >> 6) == hh) ? wvp2[((size_t)i * QS + jj) * Hc + c] : 0.f;
        } else {
            val = Wres[(size_t)i * Hc * Hc + (k - 448) * Hc + c];
        }
        v[j] = f2bf(val);
    }
    *(uint4*)&wcatF[(size_t)blk * 64 * 8 + lane * 8] = *(const uint4*)v;
}

// Wff1/Wff2: K=256, N=256
__global__ __launch_bounds__(64) void k_fff(const float* __restrict__ Wff1,
                                            const float* __restrict__ Wff2,
                                            unsigned short* __restrict__ wffF) {
    int blk = blockIdx.x;               // NLc*2*128
    int i = blk / 256;
    int rem = blk - i * 256;
    int w12 = rem >> 7;
    int r = rem & 127;
    int kk = r >> 4, ct = r & 15;
    int lane = threadIdx.x;
    int c = ct * 16 + (lane & 15);
    int kb = kk * 32 + (lane >> 4) * 8;
    const float* src = (w12 ? Wff2 : Wff1) + (size_t)i * Hc * Hc;
    unsigned short v[8];
    #pragma unroll
    for (int j = 0; j < 8; ++j) v[j] = f2bf(src[(size_t)(kb + j) * Hc + c]);
    *(uint4*)&wffF[(size_t)blk * 64 * 8 + lane * 8] = *(const uint4*)v;
}

// Wbig: K=256, N=464 (zero-padded past 452); frag (kk*29+ct)
__global__ __launch_bounds__(64) void k_fbig(const float* __restrict__ wbig,
                                             unsigned short* __restrict__ wbigF) {
    int blk = blockIdx.x;               // NLc*232
    int i = blk / 232;
    int r = blk - i * 232;
    int kk = r / 29, ct = r - kk * 29;
    int lane = threadIdx.x;
    int c = ct * 16 + (lane & 15);
    int kb = kk * 32 + (lane >> 4) * 8;
    unsigned short v[8];
    #pragma unroll
    for (int j = 0; j < 8; ++j) {
        float val = (c < Q4) ? wbig[((size_t)i * Hc + kb + j) * Q4 + c] : 0.f;
        v[j] = f2bf(val);
    }
    *(uint4*)&wbigF[(size_t)blk * 64 * 8 + lane * 8] = *(const uint4*)v;
}

// ---------------- h0 = [x_u, emb[act_u]] @ W_in_self + b
__global__ __launch_bounds__(256) void k_h0(const float* __restrict__ x_u,
                                            const int* __restrict__ act_u,
                                            const float* __restrict__ emb,
                                            const float* __restrict__ W,
                                            const float* __restrict__ bias,
                                            float* __restrict__ h) {
    constexpr int R = 16;
    int b0 = blockIdx.x * R;
    int t = threadIdx.x;
    __shared__ float xu[R * Pc];
    for (int idx = t; idx < R * Pc; idx += 256) {
        int r = idx / Pc, j = idx - r * Pc;
        int b = b0 + r;
        float v;
        if (j < Dc) v = x_u[b * Dc + j];
        else        v = emb[act_u[b] * Ec + (j - Dc)];
        xu[idx] = v;
    }
    __syncthreads();
    float acc[R];
    float bb = bias[t];
    #pragma unroll
    for (int r = 0; r < R; ++r) acc[r] = bb;
    for (int j = 0; j < Pc; ++j) {
        float w = W[j * Hc + t];
        #pragma unroll
        for (int r = 0; r < R; ++r) acc[r] += xu[r * Pc + j] * w;
    }
    #pragma unroll
    for (int r = 0; r < R; ++r) h[(b0 + r) * Hc + t] = acc[r];
}

// ---------------- prep (MFMA-transpose): xtb, xtTb, teb, teTb
__global__ __launch_bounds__(256) void k_prep(const float* __restrict__ x_ctx,
                                              const int* __restrict__ act_ctx,
                                              const float* __restrict__ emb,
                                              const float* __restrict__ t_ctx,
                                              const float* __restrict__ freq,
                                              const float* __restrict__ phase,
                                              unsigned short* __restrict__ xtb,
                                              unsigned short* __restrict__ xtTb,
                                              unsigned short* __restrict__ teb,
                                              unsigned short* __restrict__ teTb) {
    constexpr int ST = 228;
    __shared__ __align__(16) unsigned short xsT[96 * ST];
    __shared__ float lt[Lc];
    int b = blockIdx.x;
    int t = threadIdx.x;
    int wv = t >> 6, lane = t & 63;
    int m = lane & 15, kg = lane >> 4;

    if (t < Lc) lt[t] = log1pf(fmaxf(t_ctx[b * Lc + t], 0.f));

    bf16x8 ifrag[2];
    #pragma unroll
    for (int hh = 0; hh < 2; ++hh) {
        unsigned short v[8];
        #pragma unroll
        for (int j8 = 0; j8 < 8; ++j8)
            v[j8] = (kg * 8 + j8 == m + 16 * hh) ? (unsigned short)0x3F80u : (unsigned short)0;
        ifrag[hh] = *(const bf16x8*)v;
    }

    for (int tile = wv; tile < 14; tile += 4) {
        int r = tile * 16 + m;
        bool valid = r < Lc;
        bf16x8 afr[3];
        #pragma unroll
        for (int kk = 0; kk < 2; ++kk) {
            unsigned short tmp[8];
            if (valid) {
                const float* s = x_ctx + ((size_t)(b * Lc + r)) * Dc + kk * 32 + kg * 8;
                float4 a0 = *(const float4*)s;
                float4 a1 = *(const float4*)(s + 4);
                tmp[0]=f2bf(a0.x); tmp[1]=f2bf(a0.y); tmp[2]=f2bf(a0.z); tmp[3]=f2bf(a0.w);
                tmp[4]=f2bf(a1.x); tmp[5]=f2bf(a1.y); tmp[6]=f2bf(a1.z); tmp[7]=f2bf(a1.w);
            } else {
                #pragma unroll
                for (int j = 0; j < 8; ++j) tmp[j] = 0;
            }
            afr[kk] = *(const bf16x8*)tmp;
        }
        {
            unsigned short tmp[8];
            if (valid) {
                int a = act_ctx[b * Lc + r];
                const float* s = emb + (size_t)a * Ec + kg * 8;
                float4 e0 = *(const float4*)s;
                float4 e1 = *(const float4*)(s + 4);
                tmp[0]=f2bf(e0.x); tmp[1]=f2bf(e0.y); tmp[2]=f2bf(e0.z); tmp[3]=f2bf(e0.w);
                tmp[4]=f2bf(e1.x); tmp[5]=f2bf(e1.y); tmp[6]=f2bf(e1.z); tmp[7]=f2bf(e1.w);
            } else {
                #pragma unroll
                for (int j = 0; j < 8; ++j) tmp[j] = 0;
            }
            afr[2] = *(const bf16x8*)tmp;
        }
        if (valid) {
            unsigned short* dst = xtb + ((size_t)(b * Lc + r)) * 96;
            *(uint4*)(dst + kg * 8)      = *(const uint4*)&afr[0];
            *(uint4*)(dst + 32 + kg * 8) = *(const uint4*)&afr[1];
            *(uint4*)(dst + 64 + kg * 8) = *(const uint4*)&afr[2];
        }
        #pragma unroll
        for (int kk = 0; kk < 3; ++kk) {
            #pragma unroll
            for (int hh = 0; hh < 2; ++hh) {
                f32x4 d = {0.f, 0.f, 0.f, 0.f};
                d = __builtin_amdgcn_mfma_f32_16x16x32_bf16(afr[kk], ifrag[hh], d, 0, 0, 0);
                int j  = kk * 32 + hh * 16 + m;
                int l0 = tile * 16 + kg * 4;
                unsigned int u0 = (unsigned int)f2bf(d[0]) | ((unsigned int)f2bf(d[1]) << 16);
                unsigned int u1 = (unsigned int)f2bf(d[2]) | ((unsigned int)f2bf(d[3]) << 16);
                uint2 uu; uu.x = u0; uu.y = u1;
                *(uint2*)&xsT[j * ST + l0] = uu;
            }
        }
    }
    __syncthreads();

    for (int idx = t; idx < 96 * 28; idx += 256) {
        int j = idx / 28, ch = idx - j * 28;
        uint2 a  = *(const uint2*)&xsT[j * ST + ch * 8];
        uint2 b2 = *(const uint2*)&xsT[j * ST + ch * 8 + 4];
        uint4 o; o.x = a.x; o.y = a.y; o.z = b2.x; o.w = b2.y;
        *(uint4*)&xtTb[((size_t)(b * 96 + j)) * 224 + ch * 8] = o;
    }
    for (int idx = t; idx < NLc * Lc; idx += 256) {
        int i = idx / Lc, l = idx - i * Lc;
        float L = lt[l];
        unsigned short v[16];
        #pragma unroll
        for (int j = 0; j < 8; ++j) {
            float z = L * freq[i * Tc + j] + phase[i * Tc + j];
            v[j]     = f2bf(__sinf(z));
            v[8 + j] = f2bf(__cosf(z));
        }
        size_t base = ((size_t)i * TEBS + b * Lc + l) * 16;
        *(uint4*)&teb[base]     = *(const uint4*)v;
        *(uint4*)&teb[base + 8] = *(const uint4*)&v[8];
    }
    for (int idx = t; idx < NLc * 16 * 28; idx += 256) {
        int i  = idx / 448;
        int r2 = idx - i * 448;
        int f  = r2 / 28, ch = r2 - f * 28;
        int l0 = ch * 8;
        float fr = freq[i * Tc + (f & 7)], ph = phase[i * Tc + (f & 7)];
        bool iscos = f >= 8;
        unsigned short v[8];
        #pragma unroll
        for (int k = 0; k < 8; ++k) {
            int l = l0 + k;
            float val = 0.f;
            if (l < Lc) {
                float z = lt[l] * fr + ph;
                val = iscos ? __cosf(z) : __sinf(z);
            }
            v[k] = f2bf(val);
        }
        *(uint4*)&teTb[((size_t)i * Bc * 16 + b * 16 + f) * 224 + l0] = *(const uint4*)v;
    }
}

// ---------------- layer-0 qk2 (bf16 out, padded to 464)
__global__ __launch_bounds__(256) void k_qk2b(const float* __restrict__ h,
                                              const float* __restrict__ wbig_l,
                                              unsigned short* __restrict__ qk2b) {
    constexpr int R = 4;
    int rb = blockIdx.x & 255;
    int cb = blockIdx.x >> 8;
    int b0 = rb * R;
    int t = threadIdx.x;
    int c = cb * 256 + t;
    __shared__ float hl[R * Hc];
    for (int idx = t; idx < R * Hc; idx += 256) hl[idx] = h[b0 * Hc + idx];
    __syncthreads();
    if (c >= QP) return;
    if (c >= Q4) {
        #pragma unroll
        for (int r = 0; r < R; ++r) qk2b[(size_t)(b0 + r) * QP + c] = 0;
        return;
    }
    float acc[R];
    #pragma unroll
    for (int r = 0; r < R; ++r) acc[r] = 0.f;
    for (int e = 0; e < Hc; ++e) {
        float w = wbig_l[(size_t)e * Q4 + c];
        #pragma unroll
        for (int r = 0; r < R; ++r) acc[r] += hl[r * Hc + e] * w;
    }
    #pragma unroll
    for (int r = 0; r < R; ++r) qk2b[(size_t)(b0 + r) * QP + c] = f2bf(acc[r]);
}

// ---------------- fused attention, all-MFMA. One block per b, 4 waves.
__global__ __launch_bounds__(256) void k_att(const int* __restrict__ act_ctx,
                                             const unsigned short* __restrict__ qk2b,
                                             const unsigned short* __restrict__ xtb,
                                             const unsigned short* __restrict__ xtTb,
                                             const unsigned short* __restrict__ teb_l,
                                             const unsigned short* __restrict__ teTb_l,
                                             float* __restrict__ cagg) {
    __shared__ unsigned short qks[QP];
    __shared__ float S[4][208];
    __shared__ unsigned short Pl[16][232];
    int b = blockIdx.x;
    int t = threadIdx.x;
    int wv = t >> 6, lane = t & 63;
    int kg = lane >> 4;

    if (t < QP / 2) ((unsigned int*)qks)[t] = ((const unsigned int*)(qk2b + (size_t)b * QP))[t];
    __syncthreads();

    bf16x8 bfr[4];
    {
        int h = lane & 15;
        int kb = kg * 8;
        #pragma unroll
        for (int kk = 0; kk < 4; ++kk) {
            unsigned short tmp[8];
            #pragma unroll
            for (int j = 0; j < 8; ++j) {
                int k = kk * 32 + kb + j;
                tmp[j] = (h < 4 && k < QS) ? qks[h * QS + k] : (unsigned short)0;
            }
            bfr[kk] = *(const bf16x8*)tmp;
        }
    }

    const unsigned short* xrow  = xtb   + (size_t)b * Lc * 96;
    const unsigned short* terow = teb_l + (size_t)b * Lc * 16;
    for (int tile = wv; tile < 13; tile += 4) {
        int r = tile * 16 + (lane & 15);
        bf16x8 a0 = *(const bf16x8*)(xrow + (size_t)r * 96 + kg * 8);
        bf16x8 a1 = *(const bf16x8*)(xrow + (size_t)r * 96 + 32 + kg * 8);
        bf16x8 a2 = *(const bf16x8*)(xrow + (size_t)r * 96 + 64 + kg * 8);
        bf16x8 a3;
        if (kg < 2) {
            a3 = *(const bf16x8*)(terow + (size_t)r * 16 + kg * 8);
        } else if (kg == 2) {
            unsigned short tmp[8] = {0x3F80u, 0, 0, 0, 0, 0, 0, 0};
            a3 = *(const bf16x8*)tmp;
        } else {
            bf16x8 z = {0, 0, 0, 0, 0, 0, 0, 0};
            a3 = z;
        }
        f32x4 acc = {0.f, 0.f, 0.f, 0.f};
        acc = __builtin_amdgcn_mfma_f32_16x16x32_bf16(a0, bfr[0], acc, 0, 0, 0);
        acc = __builtin_amdgcn_mfma_f32_16x16x32_bf16(a1, bfr[1], acc, 0, 0, 0);
        acc = __builtin_amdgcn_mfma_f32_16x16x32_bf16(a2, bfr[2], acc, 0, 0, 0);
        acc = __builtin_amdgcn_mfma_f32_16x16x32_bf16(a3, bfr[3], acc, 0, 0, 0);
        int h = lane & 15;
        if (h < 4) {
            int rb = tile * 16 + kg * 4;
            #pragma unroll
            for (int q = 0; q < 4; ++q) S[h][rb + q] = acc[q];
        }
    }
    for (int idx = t; idx < 16 * 29; idx += 256) {
        int row = idx / 29, c8 = idx - row * 29;
        uint4 z = {0, 0, 0, 0};
        *(uint4*)&Pl[row][c8 * 8] = z;
    }
    __syncthreads();

    {
        int h = wv;
        float lv[4];
        #pragma unroll
        for (int k = 0; k < 4; ++k) {
            int l = lane + 64 * k;
            if (l < Lc) lv[k] = (act_ctx[b * Lc + l] > 0) ? S[h][l] : NEG_BIG;
            else        lv[k] = -INFINITY;
        }
        float m = fmaxf(fmaxf(lv[0], lv[1]), fmaxf(lv[2], lv[3]));
        #pragma unroll
        for (int off = 32; off >= 1; off >>= 1) m = fmaxf(m, __shfl_xor(m, off));
        float p[4];
        float ssum = 0.f;
        #pragma unroll
        for (int k = 0; k < 4; ++k) {
            int l = lane + 64 * k;
            p[k] = (l < Lc) ? __expf(lv[k] - m) : 0.f;
            ssum += p[k];
        }
        #pragma unroll
        for (int off = 32; off >= 1; off >>= 1) ssum += __shfl_xor(ssum, off);
        float sinv = 1.f / ssum;
        #pragma unroll
        for (int k = 0; k < 4; ++k) {
            int l = lane + 64 * k;
            if (l < Lc) Pl[wv][l] = f2bf(p[k] * sinv);
        }
    }
    __syncthreads();

    const unsigned short* xT  = xtTb   + (size_t)b * 96 * 224;
    const unsigned short* teT = teTb_l + (size_t)b * 16 * 224;
    for (int tile = wv; tile < 7; tile += 4) {
        int n = lane & 15;
        const unsigned short* brow = (tile < 6) ? (xT + ((size_t)(tile * 16 + n)) * 224)
                                                : (teT + (size_t)n * 224);
        f32x4 acc = {0.f, 0.f, 0.f, 0.f};
        #pragma unroll
        for (int kk = 0; kk < 7; ++kk) {
            bf16x8 a  = *(const bf16x8*)&Pl[lane & 15][kk * 32 + kg * 8];
            bf16x8 bb = *(const bf16x8*)(brow + kk * 32 + kg * 8);
            acc = __builtin_amdgcn_mfma_f32_16x16x32_bf16(a, bb, acc, 0, 0, 0);
        }
        if (kg == 0) {
            #pragma unroll
            for (int q = 0; q < 4; ++q)
                cagg[(size_t)b * CGW + q * CG + tile * 16 + n] = acc[q];
        }
    }
}

// ---------------- fused post chain + next-layer qk2, all MFMA.
// 64 blocks x 16 rows, 512 threads (8 waves).
__global__ __launch_bounds__(512) void k_postq(const float* __restrict__ cagg,
                                               float* __restrict__ h,
                                               const float* __restrict__ wvp2L,
                                               const unsigned short* __restrict__ wcatF_l,
                                               const unsigned short* __restrict__ wff1F_l,
                                               const unsigned short* __restrict__ wff2F_l,
                                               const float* __restrict__ bresL,
                                               const float* __restrict__ bff1L,
                                               const float* __restrict__ bff2L,
                                               const float* __restrict__ g1L,
                                               const float* __restrict__ beta1L,
                                               const float* __restrict__ g2L,
                                               const float* __restrict__ beta2L,
                                               const unsigned short* __restrict__ wbigF_next,
                                               unsigned short* __restrict__ qk2b) {
    __shared__ __align__(16) unsigned short Xa[16 * 712];
    __shared__ float z1f[16 * 260];
    __shared__ __align__(16) unsigned short z1n[16 * 264];
    __shared__ __align__(16) unsigned short fb16[16 * 264];
    int r0 = blockIdx.x * 16;
    int t = threadIdx.x;
    int wv = t >> 6, lane = t & 63;
    int n = lane & 15, kg = lane >> 4;

    // stage X = [cagg | h] as bf16
    for (int idx = t; idx < 16 * 704; idx += 512) {
        int r = idx / 704, c = idx - r * 704;
        float v = (c < 448) ? cagg[(size_t)(r0 + r) * CGW + c]
                            : h[(size_t)(r0 + r) * Hc + (c - 448)];
        Xa[r * 712 + c] = f2bf(v);
    }
    __syncthreads();

    // GEMM1: K=704
    {
        f32x4 acc0 = {0.f,0.f,0.f,0.f}, acc1 = {0.f,0.f,0.f,0.f};
        for (int kk = 0; kk < 22; ++kk) {
            bf16x8 a = *(const bf16x8*)&Xa[(lane & 15) * 712 + kk * 32 + kg * 8];
            bf16x8 b0 = *(const bf16x8*)(wcatF_l + (((size_t)kk * 16 + wv * 2) * 64 + lane) * 8);
            bf16x8 b1 = *(const bf16x8*)(wcatF_l + (((size_t)kk * 16 + wv * 2 + 1) * 64 + lane) * 8);
            acc0 = __builtin_amdgcn_mfma_f32_16x16x32_bf16(a, b0, acc0, 0, 0, 0);
            acc1 = __builtin_amdgcn_mfma_f32_16x16x32_bf16(a, b1, acc1, 0, 0, 0);
        }
        int c0 = (wv * 2) * 16 + n, c1 = (wv * 2 + 1) * 16 + n;
        float bi0 = bresL[c0] + wvp2L[112 * Hc + c0];
        float bi1 = bresL[c1] + wvp2L[112 * Hc + c1];
        #pragma unroll
        for (int q = 0; q < 4; ++q) {
            z1f[(kg * 4 + q) * 260 + c0] = acc0[q] + bi0;
            z1f[(kg * 4 + q) * 260 + c1] = acc1[q] + bi1;
        }
    }
    __syncthreads();
    // LN1 (waves 0-3)
    if (wv < 4) {
        int row = wv * 4 + kg;
        float sm = 0.f, sq = 0.f, vals[16];
        #pragma unroll
        for (int s = 0; s < 16; ++s) {
            float v = z1f[row * 260 + n + 16 * s];
            vals[s] = v; sm += v; sq += v * v;
        }
        #pragma unroll
        for (int off = 8; off >= 1; off >>= 1) { sm += __shfl_xor(sm, off); sq += __shfl_xor(sq, off); }
        float mu = sm * (1.f / 256.f);
        float rstd = rsqrtf(sq * (1.f / 256.f) - mu * mu + LN_EPS_V);
        #pragma unroll
        for (int s = 0; s < 16; ++s) {
            int c = n + 16 * s;
            float v = (vals[s] - mu) * rstd * g1L[c] + beta1L[c];
            z1f[row * 260 + c] = v;
            z1n[row * 264 + c] = f2bf(v);
        }
    }
    __syncthreads();
    // GEMM2 (FF1) -> relu -> fb16
    {
        f32x4 acc0 = {0.f,0.f,0.f,0.f}, acc1 = {0.f,0.f,0.f,0.f};
        for (int kk = 0; kk < 8; ++kk) {
            bf16x8 a = *(const bf16x8*)&z1n[(lane & 15) * 264 + kk * 32 + kg * 8];
            bf16x8 b0 = *(const bf16x8*)(wff1F_l + (((size_t)kk * 16 + wv * 2) * 64 + lane) * 8);
            bf16x8 b1 = *(const bf16x8*)(wff1F_l + (((size_t)kk * 16 + wv * 2 + 1) * 64 + lane) * 8);
            acc0 = __builtin_amdgcn_mfma_f32_16x16x32_bf16(a, b0, acc0, 0, 0, 0);
            acc1 = __builtin_amdgcn_mfma_f32_16x16x32_bf16(a, b1, acc1, 0, 0, 0);
        }
        int c0 = (wv * 2) * 16 + n, c1 = (wv * 2 + 1) * 16 + n;
        float bi0 = bff1L[c0], bi1 = bff1L[c1];
        #pragma unroll
        for (int q = 0; q < 4; ++q) {
            fb16[(kg * 4 + q) * 264 + c0] = f2bf(fmaxf(acc0[q] + bi0, 0.f));
            fb16[(kg * 4 + q) * 264 + c1] = f2bf(fmaxf(acc1[q] + bi1, 0.f));
        }
    }
    __syncthreads();
    // GEMM3 (FF2) + residual -> z1f
    {
        f32x4 acc0 = {0.f,0.f,0.f,0.f}, acc1 = {0.f,0.f,0.f,0.f};
        for (int kk = 0; kk < 8; ++kk) {
            bf16x8 a = *(const bf16x8*)&fb16[(lane & 15) * 264 + kk * 32 + kg * 8];
            bf16x8 b0 = *(const bf16x8*)(wff2F_l + (((size_t)kk * 16 + wv * 2) * 64 + lane) * 8);
            bf16x8 b1 = *(const bf16x8*)(wff2F_l + (((size_t)kk * 16 + wv * 2 + 1) * 64 + lane) * 8);
            acc0 = __builtin_amdgcn_mfma_f32_16x16x32_bf16(a, b0, acc0, 0, 0, 0);
            acc1 = __builtin_amdgcn_mfma_f32_16x16x32_bf16(a, b1, acc1, 0, 0, 0);
        }
        int c0 = (wv * 2) * 16 + n, c1 = (wv * 2 + 1) * 16 + n;
        float bi0 = bff2L[c0], bi1 = bff2L[c1];
        #pragma unroll
        for (int q = 0; q < 4; ++q) {
            int row = kg * 4 + q;
            z1f[row * 260 + c0] = acc0[q] + bi0 + z1f[row * 260 + c0];
            z1f[row * 260 + c1] = acc1[q] + bi1 + z1f[row * 260 + c1];
        }
    }
    __syncthreads();
    // LN2 -> h global (fp32) + z1n bf16 for qk2 GEMM
    if (wv < 4) {
        int row = wv * 4 + kg;
        float sm = 0.f, sq = 0.f, vals[16];
        #pragma unroll
        for (int s = 0; s < 16; ++s) {
            float v = z1f[row * 260 + n + 16 * s];
            vals[s] = v; sm += v; sq += v * v;
        }
        #pragma unroll
        for (int off = 8; off >= 1; off >>= 1) { sm += __shfl_xor(sm, off); sq += __shfl_xor(sq, off); }
        float mu = sm * (1.f / 256.f);
        float rstd = rsqrtf(sq * (1.f / 256.f) - mu * mu + LN_EPS_V);
        #pragma unroll
        for (int s = 0; s < 16; ++s) {
            int c = n + 16 * s;
            float v = (vals[s] - mu) * rstd * g2L[c] + beta2L[c];
            h[(size_t)(r0 + row) * Hc + c] = v;
            z1n[row * 264 + c] = f2bf(v);
        }
    }
    __syncthreads();
    // GEMM4: next-layer qk2 (K=256, N=464)
    if (wbigF_next) {
        for (int ct = wv; ct < 29; ct += 8) {
            f32x4 acc = {0.f, 0.f, 0.f, 0.f};
            for (int kk = 0; kk < 8; ++kk) {
                bf16x8 a = *(const bf16x8*)&z1n[(lane & 15) * 264 + kk * 32 + kg * 8];
                bf16x8 bb = *(const bf16x8*)(wbigF_next + (((size_t)kk * 29 + ct) * 64 + lane) * 8);
                acc = __builtin_amdgcn_mfma_f32_16x16x32_bf16(a, bb, acc, 0, 0, 0);
            }
            #pragma unroll
            for (int q = 0; q < 4; ++q)
                qk2b[(size_t)(r0 + kg * 4 + q) * QP + ct * 16 + n] = f2bf(acc[q]);
        }
    }
}

// ---------------- head
__global__ __launch_bounds__(256) void k_head(const float* __restrict__ h,
                                              const float* __restrict__ W_ro,
                                              const float* __restrict__ b_ro,
                                              const float* __restrict__ W_cls,
                                              const float* __restrict__ b_cls,
                                              const float* __restrict__ W_dt,
                                              const float* __restrict__ b_dt,
                                              const float* __restrict__ W_rem,
                                              const float* __restrict__ b_rem,
                                              float* __restrict__ out) {
    constexpr int R = 8;
    int b0 = blockIdx.x * R;
    int t = threadIdx.x;
    int wave = t >> 6, lane = t & 63;
    __shared__ float hl[R * Hc], zl[R * Hc];
    __shared__ float wcls[Hc * Cc];
    __shared__ float wdt[Hc], wrem[Hc];
    for (int idx = t; idx < R * Hc; idx += 256) hl[idx] = h[b0 * Hc + idx];
    for (int idx = t; idx < Hc * Cc; idx += 256) wcls[idx] = W_cls[idx];
    wdt[t] = W_dt[t];
    wrem[t] = W_rem[t];
    __syncthreads();
    float acc[R];
    float br = b_ro[t];
    #pragma unroll
    for (int r = 0; r < R; ++r) acc[r] = br;
    for (int d = 0; d < Hc; ++d) {
        float w = W_ro[d * Hc + t];
        #pragma unroll
        for (int r = 0; r < R; ++r) acc[r] += hl[r * Hc + d] * w;
    }
    #pragma unroll
    for (int r = 0; r < R; ++r) zl[r * Hc + t] = fmaxf(acc[r], 0.f);
    __syncthreads();
    {
        int rr = t >> 5;
        int c = t & 31;
        float a = b_cls[c];
        for (int d = 0; d < Hc; ++d) a += zl[rr * Hc + d] * wcls[d * Cc + c];
        out[(size_t)(b0 + rr) * Cc + c] = a;
    }
    for (int rr = wave * 2; rr < wave * 2 + 2; ++rr) {
        float sd = 0.f, sr = 0.f;
        #pragma unroll
        for (int k2 = 0; k2 < 4; ++k2) {
            float zv = zl[rr * Hc + lane + 64 * k2];
            sd += zv * wdt[lane + 64 * k2];
            sr += zv * wrem[lane + 64 * k2];
        }
        #pragma unroll
        for (int off = 32; off >= 1; off >>= 1) { sd += __shfl_xor(sd, off); sr += __shfl_xor(sr, off); }
        if (lane == 0) {
            out[(size_t)Bc * Cc + b0 + rr]      = 1.f / (1.f + __expf(-(sd + b_dt[0])));
            out[(size_t)Bc * Cc + Bc + b0 + rr] = 1.f / (1.f + __expf(-(sr + b_rem[0])));
        }
    }
}

extern "C" void kernel_launch(void* const* d_in, const int* in_sizes, int n_in,
                              void* d_out, int out_size, void* d_ws, size_t ws_size,
                              hipStream_t stream) {
    const float* x_u      = (const float*)d_in[0];
    const float* x_ctx    = (const float*)d_in[1];
    const float* t_ctx    = (const float*)d_in[2];
    const int*   act_u    = (const int*)d_in[3];
    const int*   act_ctx  = (const int*)d_in[4];
    const float* emb      = (const float*)d_in[5];
    const float* W_in_self = (const float*)d_in[6];
    const float* b_in_self = (const float*)d_in[7];
    const float* W_in_ctx  = (const float*)d_in[8];
    const float* b_in_ctx  = (const float*)d_in[9];
    const float* freq  = (const float*)d_in[10];
    const float* phase = (const float*)d_in[11];
    const float* Wq    = (const float*)d_in[12];
    const float* Wk    = (const float*)d_in[13];
    const float* Wv    = (const float*)d_in[14];
    const float* Wres  = (const float*)d_in[15];
    const float* bres  = (const float*)d_in[16];
    const float* Wff1  = (const float*)d_in[17];
    const float* bff1  = (const float*)d_in[18];
    const float* Wff2  = (const float*)d_in[19];
    const float* bff2  = (const float*)d_in[20];
    const float* g1    = (const float*)d_in[21];
    const float* beta1 = (const float*)d_in[22];
    const float* g2    = (const float*)d_in[23];
    const float* beta2 = (const float*)d_in[24];
    const float* W_ro  = (const float*)d_in[25];
    const float* b_ro  = (const float*)d_in[26];
    const float* W_cls = (const float*)d_in[27];
    const float* b_cls = (const float*)d_in[28];
    const float* W_dt  = (const float*)d_in[29];
    const float* b_dt  = (const float*)d_in[30];
    const float* W_rem = (const float*)d_in[31];
    const float* b_rem = (const float*)d_in[32];

    float* ws    = (float*)d_ws;
    float* hbuf  = ws;                                    // B*H
    float* wqk   = hbuf  + (size_t)Bc * Hc;               // NL*H*QKW
    float* wbig  = wqk   + (size_t)NLc * Hc * QKW;        // NL*H*Q4
    float* cagg2 = wbig  + (size_t)NLc * Hc * Q4;         // B*CGW
    float* wvp2  = cagg2 + (size_t)Bc * CGW;              // NL*QS*H
    unsigned short* xtb   = (unsigned short*)(wvp2 + (size_t)NLc * QS * Hc);
    unsigned short* xtTb  = xtb   + (size_t)XROWS * 96;
    unsigned short* teb   = xtTb  + (size_t)Bc * 96 * 224;
    unsigned short* teTb  = teb   + (size_t)NLc * TEBS * 16;
    unsigned short* qk2b  = teTb  + (size_t)NLc * Bc * 16 * 224;
    unsigned short* wcatF = qk2b  + (size_t)Bc * QP;      // NL*352*512
    unsigned short* wffF  = wcatF + (size_t)NLc * 352 * 512;  // NL*2*128*512
    unsigned short* wbigF = wffF  + (size_t)NLc * 2 * 128 * 512; // NL*232*512
    size_t need = ((size_t)Bc * Hc + (size_t)NLc * Hc * QKW + (size_t)NLc * Hc * Q4
                  + (size_t)Bc * CGW + (size_t)NLc * QS * Hc) * 4
                + ((size_t)XROWS * 96 + (size_t)Bc * 96 * 224
                  + (size_t)NLc * TEBS * 16 + (size_t)NLc * Bc * 16 * 224
                  + (size_t)Bc * QP
                  + (size_t)NLc * 352 * 512 + (size_t)NLc * 2 * 128 * 512
                  + (size_t)NLc * 232 * 512) * 2;
    if (ws_size < need) return;

    float* out = (float*)d_out;

    k_wqk<<<NLc * Hc, 256, 0, stream>>>(Wq, Wk, wqk);
    k_wbig<<<NLc * Hc, 256, 0, stream>>>(wqk, W_in_ctx, b_in_ctx, wbig);
    k_wvp<<<NLc * QS, 256, 0, stream>>>(W_in_ctx, b_in_ctx, Wv, wvp2);
    k_fcat<<<NLc * 352, 64, 0, stream>>>(wvp2, Wres, wcatF);
    k_fff<<<NLc * 256, 64, 0, stream>>>(Wff1, Wff2, wffF);
    k_fbig<<<NLc * 232, 64, 0, stream>>>(wbig, wbigF);
    k_h0<<<Bc / 16, 256, 0, stream>>>(x_u, act_u, emb, W_in_self, b_in_self, hbuf);
    k_prep<<<Bc, 256, 0, stream>>>(x_ctx, act_ctx, emb, t_ctx, freq, phase,
                                   xtb, xtTb, teb, teTb);
    k_qk2b<<<512, 256, 0, stream>>>(hbuf, wbig, qk2b);

    for (int i = 0; i < NLc; ++i) {
        k_att<<<Bc, 256, 0, stream>>>(act_ctx, qk2b, xtb, xtTb,
                                      teb + (size_t)i * TEBS * 16,
                                      teTb + (size_t)i * Bc * 16 * 224, cagg2);
        const unsigned short* wbnext = (i < NLc - 1) ? (wbigF + (size_t)(i + 1) * 232 * 512)
                                                     : (const unsigned short*)nullptr;
        k_postq<<<Bc / 16, 512, 0, stream>>>(cagg2, hbuf,
                                             wvp2 + (size_t)i * QS * Hc,
                                             wcatF + (size_t)i * 352 * 512,
                                             wffF + (size_t)(i * 2) * 128 * 512,
                                             wffF + (size_t)(i * 2 + 1) * 128 * 512,
                                             bres + i * Hc, bff1 + i * Hc, bff2 + i * Hc,
                                             g1 + i * Hc, beta1 + i * Hc,
                                             g2 + i * Hc, beta2 + i * Hc,
                                             wbnext, qk2b);
    }
    k_head<<<Bc / 8, 256, 0, stream>>>(hbuf, W_ro, b_ro, W_cls, b_cls,
                                       W_dt, b_dt, W_rem, b_rem, out);
}